// Round 3
// baseline (6199.248 us; speedup 1.0000x reference)
//
#include <hip/hip_runtime.h>
#include <cstddef>

#define NREL 4
#define HD 64
#define FD 128
#define BSHIFT 6
#define BUCKET 64      // nodes per bucket
#define CHUNK 8192     // edges per partition block

static inline int idiv_up(int a, int b) { return (a + b - 1) / b; }

// ---------------- pass A: per-relation bucket histogram ----------------

__global__ void bhist_kernel(const int* __restrict__ dst, int* __restrict__ bhist,
                             int E, int NBP) {
    int k = blockIdx.y;
    extern __shared__ int lh[];
    for (int i = threadIdx.x; i < NBP; i += blockDim.x) lh[i] = 0;
    __syncthreads();
    const int* dk = dst + (size_t)k * E;
    for (int e = blockIdx.x * blockDim.x + threadIdx.x; e < E; e += gridDim.x * blockDim.x)
        atomicAdd(&lh[dk[e] >> BSHIFT], 1);
    __syncthreads();
    int* bh = bhist + (size_t)k * NBP;
    for (int i = threadIdx.x; i < NBP; i += blockDim.x)
        if (lh[i]) atomicAdd(&bh[i], lh[i]);
}

// ---------------- pass B: exclusive scan of bucket counts (NBP <= 1024) ----------------

__global__ void bscan_kernel(const int* __restrict__ bhist, int* __restrict__ bptr,
                             int* __restrict__ gcur, int NBP, int E) {
    int k = blockIdx.x;
    __shared__ int wsum[16];
    int tid = threadIdx.x, wid = tid >> 6, lane = tid & 63;
    int v = (tid < NBP) ? bhist[(size_t)k * NBP + tid] : 0;
    int x = v;
    #pragma unroll
    for (int off = 1; off < 64; off <<= 1) {
        int y = __shfl_up(x, off, 64);
        if (lane >= off) x += y;
    }
    if (lane == 63) wsum[wid] = x;
    __syncthreads();
    if (wid == 0) {
        int s = (lane < 16) ? wsum[lane] : 0;
        #pragma unroll
        for (int off = 1; off < 16; off <<= 1) {
            int y = __shfl_up(s, off, 64);
            if (lane >= off) s += y;
        }
        if (lane < 16) wsum[lane] = s;
    }
    __syncthreads();
    int excl = x - v + (wid ? wsum[wid - 1] : 0);
    if (tid < NBP) {
        bptr[(size_t)k * (NBP + 1) + tid] = excl;
        gcur[(size_t)k * NBP + tid] = excl;
    }
    if (tid == 0) bptr[(size_t)k * (NBP + 1) + NBP] = E;
}

// ---------------- pass C: block-aggregated bucket partition ----------------
// staged[pos] = { src | (dst_local << 16), bits(w) }, grouped by bucket.

__global__ void part_kernel(const int* __restrict__ src, const int* __restrict__ dst,
                            const float* __restrict__ ew, int* __restrict__ gcur,
                            int2* __restrict__ staged, int E, int NBP) {
    int k = blockIdx.y;
    extern __shared__ int sh[];
    int* lcnt = sh;          // NBP
    int* lbase = sh + NBP;   // NBP
    for (int i = threadIdx.x; i < NBP; i += blockDim.x) lcnt[i] = 0;
    __syncthreads();
    const int* sk = src + (size_t)k * E;
    const int* dk = dst + (size_t)k * E;
    const float* wk = ew + (size_t)k * E;
    int base = blockIdx.x * CHUNK;
    int n = min(CHUNK, E - base);
    // phase 1: local bucket counts
    for (int i = threadIdx.x; i < n; i += blockDim.x)
        atomicAdd(&lcnt[dk[base + i] >> BSHIFT], 1);
    __syncthreads();
    // phase 2: reserve one contiguous run per bucket
    for (int i = threadIdx.x; i < NBP; i += blockDim.x) {
        int c = lcnt[i];
        lbase[i] = c ? atomicAdd(&gcur[(size_t)k * NBP + i], c) : 0;
    }
    __syncthreads();
    for (int i = threadIdx.x; i < NBP; i += blockDim.x) lcnt[i] = 0;
    __syncthreads();
    // phase 3: place (re-read chunk from L2)
    int2* out = staged + (size_t)k * E;
    for (int i = threadIdx.x; i < n; i += blockDim.x) {
        int d = dk[base + i];
        int b = d >> BSHIFT;
        int local = atomicAdd(&lcnt[b], 1);
        out[lbase[b] + local] =
            make_int2(sk[base + i] | ((d & (BUCKET - 1)) << 16), __float_as_int(wk[base + i]));
    }
}

// ---------------- Dense GEMM: Y[k] = X_{k%2} @ W_k  (K x 64), W in LDS ----------------

template <int K>
__global__ void gemm_kernel(const float* __restrict__ X0, const float* __restrict__ X1,
                            const float* __restrict__ Wbase, float* __restrict__ Ybase, int N) {
    __shared__ float sW[K * HD];
    int k = blockIdx.y;
    const float* X = (k & 1) ? X1 : X0;
    const float* W = Wbase + (size_t)k * K * HD;
    float* Y = Ybase + (size_t)k * N * HD;
    int tid = threadIdx.x;
    for (int i = tid * 4; i < K * HD; i += 256 * 4)
        *reinterpret_cast<float4*>(&sW[i]) = *reinterpret_cast<const float4*>(&W[i]);
    __syncthreads();
    int row = blockIdx.x * 16 + (tid >> 4);
    int col = (tid & 15) * 4;
    if (row >= N) return;
    const float* xr = X + (size_t)row * K;
    float4 acc = {0.f, 0.f, 0.f, 0.f};
    #pragma unroll 8
    for (int kk = 0; kk < K; kk += 4) {
        float4 xv = *reinterpret_cast<const float4*>(xr + kk);
        float4 w0 = *reinterpret_cast<const float4*>(&sW[(kk + 0) * HD + col]);
        float4 w1 = *reinterpret_cast<const float4*>(&sW[(kk + 1) * HD + col]);
        float4 w2 = *reinterpret_cast<const float4*>(&sW[(kk + 2) * HD + col]);
        float4 w3 = *reinterpret_cast<const float4*>(&sW[(kk + 3) * HD + col]);
        acc.x += xv.x * w0.x + xv.y * w1.x + xv.z * w2.x + xv.w * w3.x;
        acc.y += xv.x * w0.y + xv.y * w1.y + xv.z * w2.y + xv.w * w3.y;
        acc.z += xv.x * w0.z + xv.y * w1.z + xv.z * w2.z + xv.w * w3.z;
        acc.w += xv.x * w0.w + xv.y * w1.w + xv.z * w2.w + xv.w * w3.w;
    }
    *reinterpret_cast<float4*>(&Y[(size_t)row * HD + col]) = acc;
}

// ---------------- SpMM: block per (bucket, type), LDS accumulator ----------------

__global__ void spmm_kernel(const float* __restrict__ Ybase, const int* __restrict__ bptr,
                            const int2* __restrict__ staged,
                            float* __restrict__ act, float* __restrict__ outp,
                            int N, int E, int NBP, int relu) {
    int t = blockIdx.y;
    int b = blockIdx.x;
    __shared__ float acc[BUCKET * HD];   // 16 KiB
    int tid = threadIdx.x;
    for (int i = tid; i < BUCKET * HD; i += 256) acc[i] = 0.f;
    __syncthreads();
    int wave = tid >> 6, lane = tid & 63;
    #pragma unroll
    for (int rr = 0; rr < 2; ++rr) {
        int r = 2 * t + rr;
        const float* Y = Ybase + (size_t)r * N * HD;
        const int2* ep = staged + (size_t)r * E;
        int beg = bptr[(size_t)r * (NBP + 1) + b];
        int len = bptr[(size_t)r * (NBP + 1) + b + 1] - beg;
        for (int i = wave * 4; i < len; i += 16) {
            if (i + 4 <= len) {
                int2 q0 = ep[beg + i + 0];
                int2 q1 = ep[beg + i + 1];
                int2 q2 = ep[beg + i + 2];
                int2 q3 = ep[beg + i + 3];
                float y0 = Y[(size_t)(q0.x & 0xFFFF) * HD + lane];
                float y1 = Y[(size_t)(q1.x & 0xFFFF) * HD + lane];
                float y2 = Y[(size_t)(q2.x & 0xFFFF) * HD + lane];
                float y3 = Y[(size_t)(q3.x & 0xFFFF) * HD + lane];
                atomicAdd(&acc[(q0.x >> 16) * HD + lane], __int_as_float(q0.y) * y0);
                atomicAdd(&acc[(q1.x >> 16) * HD + lane], __int_as_float(q1.y) * y1);
                atomicAdd(&acc[(q2.x >> 16) * HD + lane], __int_as_float(q2.y) * y2);
                atomicAdd(&acc[(q3.x >> 16) * HD + lane], __int_as_float(q3.y) * y3);
            } else {
                for (int j = i; j < len; ++j) {
                    int2 q = ep[beg + j];
                    float y = Y[(size_t)(q.x & 0xFFFF) * HD + lane];
                    atomicAdd(&acc[(q.x >> 16) * HD + lane], __int_as_float(q.y) * y);
                }
            }
        }
    }
    __syncthreads();
    int node0 = b * BUCKET;
    for (int i = tid; i < BUCKET * HD; i += 256) {
        int row = i >> 6;
        int col = i & 63;
        int node = node0 + row;
        if (node < N) {
            float v = acc[i];
            if (relu) v = fmaxf(v, 0.f);
            if (act)  act[((size_t)t * N + node) * HD + col] = v;
            if (outp) outp[((size_t)t * N + node) * 192 + col] = v;
        }
    }
}

// ---------------- orchestration ----------------

extern "C" void kernel_launch(void* const* d_in, const int* in_sizes, int n_in,
                              void* d_out, int out_size, void* d_ws, size_t ws_size,
                              hipStream_t stream) {
    const float* x0 = (const float*)d_in[0];
    const float* x1 = (const float*)d_in[1];
    const int* src = (const int*)d_in[2];
    const int* dst = (const int*)d_in[3];
    const float* ew = (const float*)d_in[4];
    const float* W1 = (const float*)d_in[5];
    const float* Wl = (const float*)d_in[6];
    float* out = (float*)d_out;

    int N = in_sizes[0] / FD;
    int E = in_sizes[2] / NREL;
    int NBP = idiv_up(N, BUCKET);   // 782 for N=50000 (must be <= 1024 for bscan)

    char* ws = (char*)d_ws;
    size_t off = 0;
    auto alloc = [&](size_t bytes) -> void* {
        void* p = ws + off;
        off = (off + bytes + 255) & ~(size_t)255;
        return p;
    };
    int* bhist   = (int*)alloc((size_t)NREL * NBP * 4);
    int* bptr    = (int*)alloc((size_t)NREL * (NBP + 1) * 4);
    int* gcur    = (int*)alloc((size_t)NREL * NBP * 4);
    int2* staged = (int2*)alloc((size_t)NREL * E * 8);
    float* y     = (float*)alloc((size_t)NREL * N * HD * 4);
    float* act   = (float*)alloc((size_t)2 * N * HD * 4);
    (void)ws_size;

    // bucket partition (recomputed every call; inputs never mutated)
    hipMemsetAsync(bhist, 0, (size_t)NREL * NBP * 4, stream);
    dim3 egrid(idiv_up(E, CHUNK), NREL);
    bhist_kernel<<<egrid, 256, NBP * 4, stream>>>(dst, bhist, E, NBP);
    bscan_kernel<<<NREL, 1024, 0, stream>>>(bhist, bptr, gcur, NBP, E);
    part_kernel<<<egrid, 256, 2 * NBP * 4, stream>>>(src, dst, ew, gcur, staged, E, NBP);

    dim3 ggrid(idiv_up(N, 16), NREL);
    dim3 sgrid(NBP, 2);

    // layer 1: h1 = relu(spmm(x @ W1)); store act + out[:, :, 0:64]
    gemm_kernel<FD><<<ggrid, 256, 0, stream>>>(x0, x1, W1, y, N);
    spmm_kernel<<<sgrid, 256, 0, stream>>>(y, bptr, staged, act, out + 0, N, E, NBP, 1);

    // layers 2..5 with Wl[0..3]
    for (int l = 0; l < 4; ++l) {
        gemm_kernel<HD><<<ggrid, 256, 0, stream>>>(act, act + (size_t)N * HD,
                                                   Wl + (size_t)l * NREL * HD * HD, y, N);
        float* op = (l == 0) ? (out + 64) : (l == 3) ? (out + 128) : nullptr;
        float* ap = (l == 3) ? nullptr : act;
        int relu = (l == 3) ? 0 : 1;
        spmm_kernel<<<sgrid, 256, 0, stream>>>(y, bptr, staged, ap, op, N, E, NBP, relu);
    }
}

// Round 4
// 925.165 us; speedup vs baseline: 6.7007x; 6.7007x over previous
//
#include <hip/hip_runtime.h>
#include <cstddef>

#define NREL 4
#define HD 64
#define FD 128
#define BSHIFT 6
#define BUCKET 64      // nodes per bucket
#define CHUNK 8192     // edges per partition block

static inline int idiv_up(int a, int b) { return (a + b - 1) / b; }

// ---------------- pass A: per-relation bucket histogram ----------------

__global__ void bhist_kernel(const int* __restrict__ dst, int* __restrict__ bhist,
                             int E, int NBP) {
    int k = blockIdx.y;
    extern __shared__ int lh[];
    for (int i = threadIdx.x; i < NBP; i += blockDim.x) lh[i] = 0;
    __syncthreads();
    const int* dk = dst + (size_t)k * E;
    for (int e = blockIdx.x * blockDim.x + threadIdx.x; e < E; e += gridDim.x * blockDim.x)
        atomicAdd(&lh[dk[e] >> BSHIFT], 1);
    __syncthreads();
    int* bh = bhist + (size_t)k * NBP;
    for (int i = threadIdx.x; i < NBP; i += blockDim.x)
        if (lh[i]) atomicAdd(&bh[i], lh[i]);
}

// ---------------- pass B: exclusive scan of bucket counts (NBP <= 1024) ----------------

__global__ void bscan_kernel(const int* __restrict__ bhist, int* __restrict__ bptr,
                             int* __restrict__ gcur, int NBP, int E) {
    int k = blockIdx.x;
    __shared__ int wsum[16];
    int tid = threadIdx.x, wid = tid >> 6, lane = tid & 63;
    int v = (tid < NBP) ? bhist[(size_t)k * NBP + tid] : 0;
    int x = v;
    #pragma unroll
    for (int off = 1; off < 64; off <<= 1) {
        int y = __shfl_up(x, off, 64);
        if (lane >= off) x += y;
    }
    if (lane == 63) wsum[wid] = x;
    __syncthreads();
    if (wid == 0) {
        int s = (lane < 16) ? wsum[lane] : 0;
        #pragma unroll
        for (int off = 1; off < 16; off <<= 1) {
            int y = __shfl_up(s, off, 64);
            if (lane >= off) s += y;
        }
        if (lane < 16) wsum[lane] = s;
    }
    __syncthreads();
    int excl = x - v + (wid ? wsum[wid - 1] : 0);
    if (tid < NBP) {
        bptr[(size_t)k * (NBP + 1) + tid] = excl;
        gcur[(size_t)k * NBP + tid] = excl;
    }
    if (tid == 0) bptr[(size_t)k * (NBP + 1) + NBP] = E;
}

// ---------------- pass C: block-aggregated bucket partition ----------------
// staged[pos] = { src | (dst_local << 16), bits(w) }, grouped by bucket.

__global__ void part_kernel(const int* __restrict__ src, const int* __restrict__ dst,
                            const float* __restrict__ ew, int* __restrict__ gcur,
                            int2* __restrict__ staged, int E, int NBP) {
    int k = blockIdx.y;
    extern __shared__ int sh[];
    int* lcnt = sh;          // NBP
    int* lbase = sh + NBP;   // NBP
    for (int i = threadIdx.x; i < NBP; i += blockDim.x) lcnt[i] = 0;
    __syncthreads();
    const int* sk = src + (size_t)k * E;
    const int* dk = dst + (size_t)k * E;
    const float* wk = ew + (size_t)k * E;
    int base = blockIdx.x * CHUNK;
    int n = min(CHUNK, E - base);
    // phase 1: local bucket counts
    for (int i = threadIdx.x; i < n; i += blockDim.x)
        atomicAdd(&lcnt[dk[base + i] >> BSHIFT], 1);
    __syncthreads();
    // phase 2: reserve one contiguous run per bucket
    for (int i = threadIdx.x; i < NBP; i += blockDim.x) {
        int c = lcnt[i];
        lbase[i] = c ? atomicAdd(&gcur[(size_t)k * NBP + i], c) : 0;
    }
    __syncthreads();
    for (int i = threadIdx.x; i < NBP; i += blockDim.x) lcnt[i] = 0;
    __syncthreads();
    // phase 3: place (re-read chunk from L2)
    int2* out = staged + (size_t)k * E;
    for (int i = threadIdx.x; i < n; i += blockDim.x) {
        int d = dk[base + i];
        int b = d >> BSHIFT;
        int local = atomicAdd(&lcnt[b], 1);
        out[lbase[b] + local] =
            make_int2(sk[base + i] | ((d & (BUCKET - 1)) << 16), __float_as_int(wk[base + i]));
    }
}

// ---------------- pass D: per-bucket LDS counting sort -> node-sorted edges + rowptr ----

__global__ void bsort_kernel(const int2* __restrict__ staged, const int* __restrict__ bptr,
                             int* __restrict__ rowptr, int2* __restrict__ edges,
                             int E, int N, int NBP) {
    int k = blockIdx.y;
    int b = blockIdx.x;
    __shared__ int hist[BUCKET];
    __shared__ int excl[BUCKET];
    __shared__ int cur[BUCKET];
    int tid = threadIdx.x;
    if (tid < BUCKET) hist[tid] = 0;
    __syncthreads();
    int beg = bptr[(size_t)k * (NBP + 1) + b];
    int end = bptr[(size_t)k * (NBP + 1) + b + 1];
    const int2* in = staged + (size_t)k * E;
    for (int i = beg + tid; i < end; i += blockDim.x)
        atomicAdd(&hist[(in[i].x >> 16) & (BUCKET - 1)], 1);
    __syncthreads();
    if (tid < 64) {   // full wave 0: exclusive scan of 64 counts
        int v = hist[tid];
        int x = v;
        #pragma unroll
        for (int off = 1; off < 64; off <<= 1) {
            int y = __shfl_up(x, off, 64);
            if (tid >= off) x += y;
        }
        excl[tid] = x - v;
        cur[tid] = x - v;
    }
    __syncthreads();
    int2* outp = edges + (size_t)k * E;
    for (int i = beg + tid; i < end; i += blockDim.x) {
        int2 q = in[i];
        int dl = (q.x >> 16) & (BUCKET - 1);
        int pos = atomicAdd(&cur[dl], 1);
        outp[beg + pos] = make_int2(q.x & 0xFFFF, q.y);
    }
    int node0 = b * BUCKET;
    if (tid < BUCKET && node0 + tid < N)
        rowptr[(size_t)k * (N + 1) + node0 + tid] = beg + excl[tid];
    if (b == 0 && tid == 0) rowptr[(size_t)k * (N + 1) + N] = E;
}

// ---------------- Dense GEMM: Y[k] = X_{k%2} @ W_k  (K x 64), W in LDS ----------------

template <int K>
__global__ void gemm_kernel(const float* __restrict__ X0, const float* __restrict__ X1,
                            const float* __restrict__ Wbase, float* __restrict__ Ybase, int N) {
    __shared__ float sW[K * HD];
    int k = blockIdx.y;
    const float* X = (k & 1) ? X1 : X0;
    const float* W = Wbase + (size_t)k * K * HD;
    float* Y = Ybase + (size_t)k * N * HD;
    int tid = threadIdx.x;
    for (int i = tid * 4; i < K * HD; i += 256 * 4)
        *reinterpret_cast<float4*>(&sW[i]) = *reinterpret_cast<const float4*>(&W[i]);
    __syncthreads();
    int row = blockIdx.x * 16 + (tid >> 4);
    int col = (tid & 15) * 4;
    if (row >= N) return;
    const float* xr = X + (size_t)row * K;
    float4 acc = {0.f, 0.f, 0.f, 0.f};
    #pragma unroll 8
    for (int kk = 0; kk < K; kk += 4) {
        float4 xv = *reinterpret_cast<const float4*>(xr + kk);
        float4 w0 = *reinterpret_cast<const float4*>(&sW[(kk + 0) * HD + col]);
        float4 w1 = *reinterpret_cast<const float4*>(&sW[(kk + 1) * HD + col]);
        float4 w2 = *reinterpret_cast<const float4*>(&sW[(kk + 2) * HD + col]);
        float4 w3 = *reinterpret_cast<const float4*>(&sW[(kk + 3) * HD + col]);
        acc.x += xv.x * w0.x + xv.y * w1.x + xv.z * w2.x + xv.w * w3.x;
        acc.y += xv.x * w0.y + xv.y * w1.y + xv.z * w2.y + xv.w * w3.y;
        acc.z += xv.x * w0.z + xv.y * w1.z + xv.z * w2.z + xv.w * w3.z;
        acc.w += xv.x * w0.w + xv.y * w1.w + xv.z * w2.w + xv.w * w3.w;
    }
    *reinterpret_cast<float4*>(&Y[(size_t)row * HD + col]) = acc;
}

// ---------------- SpMM gather: one wave per dst node, lane = feature ----------------
// out_type t accumulates relations 2t (src x0-side) and 2t+1 (src x1-side).
// 8 independent gathers in flight per wave.

__global__ void spmm_kernel(const float* __restrict__ Ybase, const int* __restrict__ rowptr,
                            const int2* __restrict__ edges,
                            float* __restrict__ act, float* __restrict__ outp,
                            int N, int E, int relu) {
    int t = blockIdx.y;
    int wave = threadIdx.x >> 6;
    int lane = threadIdx.x & 63;
    int d = blockIdx.x * 4 + wave;
    if (d >= N) return;
    float a0 = 0.f, a1 = 0.f, a2 = 0.f, a3 = 0.f;
    float a4 = 0.f, a5 = 0.f, a6 = 0.f, a7 = 0.f;
    #pragma unroll
    for (int rr = 0; rr < 2; ++rr) {
        int r = 2 * t + rr;
        const float* Y = Ybase + (size_t)r * N * HD;
        const int2* ep = edges + (size_t)r * E;
        int e = rowptr[(size_t)r * (N + 1) + d];
        int end = rowptr[(size_t)r * (N + 1) + d + 1];
        for (; e + 8 <= end; e += 8) {
            int2 e0 = ep[e + 0];
            int2 e1 = ep[e + 1];
            int2 e2 = ep[e + 2];
            int2 e3 = ep[e + 3];
            int2 e4 = ep[e + 4];
            int2 e5 = ep[e + 5];
            int2 e6 = ep[e + 6];
            int2 e7 = ep[e + 7];
            float y0 = Y[(size_t)e0.x * HD + lane];
            float y1 = Y[(size_t)e1.x * HD + lane];
            float y2 = Y[(size_t)e2.x * HD + lane];
            float y3 = Y[(size_t)e3.x * HD + lane];
            float y4 = Y[(size_t)e4.x * HD + lane];
            float y5 = Y[(size_t)e5.x * HD + lane];
            float y6 = Y[(size_t)e6.x * HD + lane];
            float y7 = Y[(size_t)e7.x * HD + lane];
            a0 += __int_as_float(e0.y) * y0;
            a1 += __int_as_float(e1.y) * y1;
            a2 += __int_as_float(e2.y) * y2;
            a3 += __int_as_float(e3.y) * y3;
            a4 += __int_as_float(e4.y) * y4;
            a5 += __int_as_float(e5.y) * y5;
            a6 += __int_as_float(e6.y) * y6;
            a7 += __int_as_float(e7.y) * y7;
        }
        if (e + 4 <= end) {
            int2 e0 = ep[e + 0];
            int2 e1 = ep[e + 1];
            int2 e2 = ep[e + 2];
            int2 e3 = ep[e + 3];
            float y0 = Y[(size_t)e0.x * HD + lane];
            float y1 = Y[(size_t)e1.x * HD + lane];
            float y2 = Y[(size_t)e2.x * HD + lane];
            float y3 = Y[(size_t)e3.x * HD + lane];
            a0 += __int_as_float(e0.y) * y0;
            a1 += __int_as_float(e1.y) * y1;
            a2 += __int_as_float(e2.y) * y2;
            a3 += __int_as_float(e3.y) * y3;
            e += 4;
        }
        for (; e < end; ++e) {
            int2 ee = ep[e];
            a0 += __int_as_float(ee.y) * Y[(size_t)ee.x * HD + lane];
        }
    }
    float acc = ((a0 + a1) + (a2 + a3)) + ((a4 + a5) + (a6 + a7));
    if (relu) acc = fmaxf(acc, 0.f);
    if (act) act[((size_t)t * N + d) * HD + lane] = acc;
    if (outp) outp[((size_t)t * N + d) * 192 + lane] = acc;
}

// ---------------- orchestration ----------------

extern "C" void kernel_launch(void* const* d_in, const int* in_sizes, int n_in,
                              void* d_out, int out_size, void* d_ws, size_t ws_size,
                              hipStream_t stream) {
    const float* x0 = (const float*)d_in[0];
    const float* x1 = (const float*)d_in[1];
    const int* src = (const int*)d_in[2];
    const int* dst = (const int*)d_in[3];
    const float* ew = (const float*)d_in[4];
    const float* W1 = (const float*)d_in[5];
    const float* Wl = (const float*)d_in[6];
    float* out = (float*)d_out;

    int N = in_sizes[0] / FD;
    int E = in_sizes[2] / NREL;
    int NBP = idiv_up(N, BUCKET);   // 782 for N=50000 (must be <= 1024 for bscan)

    char* ws = (char*)d_ws;
    size_t off = 0;
    auto alloc = [&](size_t bytes) -> void* {
        void* p = ws + off;
        off = (off + bytes + 255) & ~(size_t)255;
        return p;
    };
    int* bhist   = (int*)alloc((size_t)NREL * NBP * 4);
    int* bptr    = (int*)alloc((size_t)NREL * (NBP + 1) * 4);
    int* gcur    = (int*)alloc((size_t)NREL * NBP * 4);
    int* rowptr  = (int*)alloc((size_t)NREL * (N + 1) * 4);
    int2* edges  = (int2*)alloc((size_t)NREL * E * 8);
    float* y     = (float*)alloc((size_t)NREL * N * HD * 4);
    float* act   = (float*)alloc((size_t)2 * N * HD * 4);
    // staged (bucket-grouped) is dead after bsort; alias it over y (written later)
    int2* staged = (int2*)y;   // NREL*E*8 = 25.6MB <= y's 51.2MB
    (void)ws_size;

    // bucket partition + per-bucket counting sort (recomputed every call)
    hipMemsetAsync(bhist, 0, (size_t)NREL * NBP * 4, stream);
    dim3 egrid(idiv_up(E, CHUNK), NREL);
    bhist_kernel<<<egrid, 256, NBP * 4, stream>>>(dst, bhist, E, NBP);
    bscan_kernel<<<NREL, 1024, 0, stream>>>(bhist, bptr, gcur, NBP, E);
    part_kernel<<<egrid, 256, 2 * NBP * 4, stream>>>(src, dst, ew, gcur, staged, E, NBP);
    bsort_kernel<<<dim3(NBP, NREL), 256, 0, stream>>>(staged, bptr, rowptr, edges, E, N, NBP);

    dim3 ggrid(idiv_up(N, 16), NREL);
    dim3 sgrid(idiv_up(N, 4), 2);

    // layer 1: h1 = relu(spmm(x @ W1)); store act + out[:, :, 0:64]
    gemm_kernel<FD><<<ggrid, 256, 0, stream>>>(x0, x1, W1, y, N);
    spmm_kernel<<<sgrid, 256, 0, stream>>>(y, rowptr, edges, act, out + 0, N, E, 1);

    // layers 2..5 with Wl[0..3]
    for (int l = 0; l < 4; ++l) {
        gemm_kernel<HD><<<ggrid, 256, 0, stream>>>(act, act + (size_t)N * HD,
                                                   Wl + (size_t)l * NREL * HD * HD, y, N);
        float* op = (l == 0) ? (out + 64) : (l == 3) ? (out + 128) : nullptr;
        float* ap = (l == 3) ? nullptr : act;
        int relu = (l == 3) ? 0 : 1;
        spmm_kernel<<<sgrid, 256, 0, stream>>>(y, rowptr, edges, ap, op, N, E, relu);
    }
}

// Round 5
// 838.267 us; speedup vs baseline: 7.3953x; 1.1037x over previous
//
#include <hip/hip_runtime.h>
#include <cstddef>

#define NREL 4
#define HD 64
#define FD 128
#define BSHIFT 6
#define BUCKET 64      // nodes per bucket
#define CHUNK 8192     // edges per partition block

static inline int idiv_up(int a, int b) { return (a + b - 1) / b; }

__device__ __forceinline__ unsigned short f2bf(float f) {
    unsigned int u = __float_as_uint(f);
    unsigned int r = (u + 0x7FFFu + ((u >> 16) & 1u)) >> 16;   // RNE
    return (unsigned short)r;
}
__device__ __forceinline__ float bf2f(unsigned short v) {
    return __uint_as_float((unsigned int)v << 16);
}

// ---------------- pass A: per-relation bucket histogram ----------------

__global__ void bhist_kernel(const int* __restrict__ dst, int* __restrict__ bhist,
                             int E, int NBP) {
    int k = blockIdx.y;
    extern __shared__ int lh[];
    for (int i = threadIdx.x; i < NBP; i += blockDim.x) lh[i] = 0;
    __syncthreads();
    const int* dk = dst + (size_t)k * E;
    for (int e = blockIdx.x * blockDim.x + threadIdx.x; e < E; e += gridDim.x * blockDim.x)
        atomicAdd(&lh[dk[e] >> BSHIFT], 1);
    __syncthreads();
    int* bh = bhist + (size_t)k * NBP;
    for (int i = threadIdx.x; i < NBP; i += blockDim.x)
        if (lh[i]) atomicAdd(&bh[i], lh[i]);
}

// ---------------- pass B: exclusive scan of bucket counts (NBP <= 1024) ----------------

__global__ void bscan_kernel(const int* __restrict__ bhist, int* __restrict__ bptr,
                             int* __restrict__ gcur, int NBP, int E) {
    int k = blockIdx.x;
    __shared__ int wsum[16];
    int tid = threadIdx.x, wid = tid >> 6, lane = tid & 63;
    int v = (tid < NBP) ? bhist[(size_t)k * NBP + tid] : 0;
    int x = v;
    #pragma unroll
    for (int off = 1; off < 64; off <<= 1) {
        int y = __shfl_up(x, off, 64);
        if (lane >= off) x += y;
    }
    if (lane == 63) wsum[wid] = x;
    __syncthreads();
    if (wid == 0) {
        int s = (lane < 16) ? wsum[lane] : 0;
        #pragma unroll
        for (int off = 1; off < 16; off <<= 1) {
            int y = __shfl_up(s, off, 64);
            if (lane >= off) s += y;
        }
        if (lane < 16) wsum[lane] = s;
    }
    __syncthreads();
    int excl = x - v + (wid ? wsum[wid - 1] : 0);
    if (tid < NBP) {
        bptr[(size_t)k * (NBP + 1) + tid] = excl;
        gcur[(size_t)k * NBP + tid] = excl;
    }
    if (tid == 0) bptr[(size_t)k * (NBP + 1) + NBP] = E;
}

// ---------------- pass C: block-aggregated bucket partition ----------------
// staged[pos] = { src | (dst_local << 16), bits(w) }, grouped by bucket.

__global__ void part_kernel(const int* __restrict__ src, const int* __restrict__ dst,
                            const float* __restrict__ ew, int* __restrict__ gcur,
                            int2* __restrict__ staged, int E, int NBP) {
    int k = blockIdx.y;
    extern __shared__ int sh[];
    int* lcnt = sh;          // NBP
    int* lbase = sh + NBP;   // NBP
    for (int i = threadIdx.x; i < NBP; i += blockDim.x) lcnt[i] = 0;
    __syncthreads();
    const int* sk = src + (size_t)k * E;
    const int* dk = dst + (size_t)k * E;
    const float* wk = ew + (size_t)k * E;
    int base = blockIdx.x * CHUNK;
    int n = min(CHUNK, E - base);
    for (int i = threadIdx.x; i < n; i += blockDim.x)
        atomicAdd(&lcnt[dk[base + i] >> BSHIFT], 1);
    __syncthreads();
    for (int i = threadIdx.x; i < NBP; i += blockDim.x) {
        int c = lcnt[i];
        lbase[i] = c ? atomicAdd(&gcur[(size_t)k * NBP + i], c) : 0;
    }
    __syncthreads();
    for (int i = threadIdx.x; i < NBP; i += blockDim.x) lcnt[i] = 0;
    __syncthreads();
    int2* out = staged + (size_t)k * E;
    for (int i = threadIdx.x; i < n; i += blockDim.x) {
        int d = dk[base + i];
        int b = d >> BSHIFT;
        int local = atomicAdd(&lcnt[b], 1);
        out[lbase[b] + local] =
            make_int2(sk[base + i] | ((d & (BUCKET - 1)) << 16), __float_as_int(wk[base + i]));
    }
}

// ---------------- pass D: per-bucket LDS counting sort -> node-sorted edges + rowptr ----

__global__ void bsort_kernel(const int2* __restrict__ staged, const int* __restrict__ bptr,
                             int* __restrict__ rowptr, int2* __restrict__ edges,
                             int E, int N, int NBP) {
    int k = blockIdx.y;
    int b = blockIdx.x;
    __shared__ int hist[BUCKET];
    __shared__ int excl[BUCKET];
    __shared__ int cur[BUCKET];
    int tid = threadIdx.x;
    if (tid < BUCKET) hist[tid] = 0;
    __syncthreads();
    int beg = bptr[(size_t)k * (NBP + 1) + b];
    int end = bptr[(size_t)k * (NBP + 1) + b + 1];
    const int2* in = staged + (size_t)k * E;
    for (int i = beg + tid; i < end; i += blockDim.x)
        atomicAdd(&hist[(in[i].x >> 16) & (BUCKET - 1)], 1);
    __syncthreads();
    if (tid < 64) {
        int v = hist[tid];
        int x = v;
        #pragma unroll
        for (int off = 1; off < 64; off <<= 1) {
            int y = __shfl_up(x, off, 64);
            if (tid >= off) x += y;
        }
        excl[tid] = x - v;
        cur[tid] = x - v;
    }
    __syncthreads();
    int2* outp = edges + (size_t)k * E;
    for (int i = beg + tid; i < end; i += blockDim.x) {
        int2 q = in[i];
        int dl = (q.x >> 16) & (BUCKET - 1);
        int pos = atomicAdd(&cur[dl], 1);
        outp[beg + pos] = make_int2(q.x & 0xFFFF, q.y);
    }
    int node0 = b * BUCKET;
    if (tid < BUCKET && node0 + tid < N)
        rowptr[(size_t)k * (N + 1) + node0 + tid] = beg + excl[tid];
    if (b == 0 && tid == 0) rowptr[(size_t)k * (N + 1) + N] = E;
}

// ---------------- Dense GEMM: Y[k] = X_{k%2} @ W_k  (K x 64), bf16 output ----------------

template <int K>
__global__ void gemm_kernel(const float* __restrict__ X0, const float* __restrict__ X1,
                            const float* __restrict__ Wbase, unsigned short* __restrict__ Ybase,
                            int N) {
    __shared__ float sW[K * HD];
    int k = blockIdx.y;
    const float* X = (k & 1) ? X1 : X0;
    const float* W = Wbase + (size_t)k * K * HD;
    unsigned short* Y = Ybase + (size_t)k * N * HD;
    int tid = threadIdx.x;
    for (int i = tid * 4; i < K * HD; i += 256 * 4)
        *reinterpret_cast<float4*>(&sW[i]) = *reinterpret_cast<const float4*>(&W[i]);
    __syncthreads();
    int row = blockIdx.x * 16 + (tid >> 4);
    int col = (tid & 15) * 4;
    if (row >= N) return;
    const float* xr = X + (size_t)row * K;
    float4 acc = {0.f, 0.f, 0.f, 0.f};
    #pragma unroll 8
    for (int kk = 0; kk < K; kk += 4) {
        float4 xv = *reinterpret_cast<const float4*>(xr + kk);
        float4 w0 = *reinterpret_cast<const float4*>(&sW[(kk + 0) * HD + col]);
        float4 w1 = *reinterpret_cast<const float4*>(&sW[(kk + 1) * HD + col]);
        float4 w2 = *reinterpret_cast<const float4*>(&sW[(kk + 2) * HD + col]);
        float4 w3 = *reinterpret_cast<const float4*>(&sW[(kk + 3) * HD + col]);
        acc.x += xv.x * w0.x + xv.y * w1.x + xv.z * w2.x + xv.w * w3.x;
        acc.y += xv.x * w0.y + xv.y * w1.y + xv.z * w2.y + xv.w * w3.y;
        acc.z += xv.x * w0.z + xv.y * w1.z + xv.z * w2.z + xv.w * w3.z;
        acc.w += xv.x * w0.w + xv.y * w1.w + xv.z * w2.w + xv.w * w3.w;
    }
    ushort4 o;
    o.x = f2bf(acc.x); o.y = f2bf(acc.y); o.z = f2bf(acc.z); o.w = f2bf(acc.w);
    *reinterpret_cast<ushort4*>(&Y[(size_t)row * HD + col]) = o;
}

// ---------------- SpMM gather: one wave per dst node, lane = feature ----------------
// Y rows are bf16 (128 B); accumulate in f32; 8 gathers in flight.

__global__ void spmm_kernel(const unsigned short* __restrict__ Ybase,
                            const int* __restrict__ rowptr, const int2* __restrict__ edges,
                            float* __restrict__ act, float* __restrict__ outp,
                            int N, int E, int relu) {
    int t = blockIdx.y;
    int wave = threadIdx.x >> 6;
    int lane = threadIdx.x & 63;
    int d = blockIdx.x * 4 + wave;
    if (d >= N) return;
    float a0 = 0.f, a1 = 0.f, a2 = 0.f, a3 = 0.f;
    float a4 = 0.f, a5 = 0.f, a6 = 0.f, a7 = 0.f;
    #pragma unroll
    for (int rr = 0; rr < 2; ++rr) {
        int r = 2 * t + rr;
        const unsigned short* Y = Ybase + (size_t)r * N * HD;
        const int2* ep = edges + (size_t)r * E;
        int e = rowptr[(size_t)r * (N + 1) + d];
        int end = rowptr[(size_t)r * (N + 1) + d + 1];
        for (; e + 8 <= end; e += 8) {
            int2 e0 = ep[e + 0];
            int2 e1 = ep[e + 1];
            int2 e2 = ep[e + 2];
            int2 e3 = ep[e + 3];
            int2 e4 = ep[e + 4];
            int2 e5 = ep[e + 5];
            int2 e6 = ep[e + 6];
            int2 e7 = ep[e + 7];
            unsigned short y0 = Y[(size_t)e0.x * HD + lane];
            unsigned short y1 = Y[(size_t)e1.x * HD + lane];
            unsigned short y2 = Y[(size_t)e2.x * HD + lane];
            unsigned short y3 = Y[(size_t)e3.x * HD + lane];
            unsigned short y4 = Y[(size_t)e4.x * HD + lane];
            unsigned short y5 = Y[(size_t)e5.x * HD + lane];
            unsigned short y6 = Y[(size_t)e6.x * HD + lane];
            unsigned short y7 = Y[(size_t)e7.x * HD + lane];
            a0 += __int_as_float(e0.y) * bf2f(y0);
            a1 += __int_as_float(e1.y) * bf2f(y1);
            a2 += __int_as_float(e2.y) * bf2f(y2);
            a3 += __int_as_float(e3.y) * bf2f(y3);
            a4 += __int_as_float(e4.y) * bf2f(y4);
            a5 += __int_as_float(e5.y) * bf2f(y5);
            a6 += __int_as_float(e6.y) * bf2f(y6);
            a7 += __int_as_float(e7.y) * bf2f(y7);
        }
        if (e + 4 <= end) {
            int2 e0 = ep[e + 0];
            int2 e1 = ep[e + 1];
            int2 e2 = ep[e + 2];
            int2 e3 = ep[e + 3];
            unsigned short y0 = Y[(size_t)e0.x * HD + lane];
            unsigned short y1 = Y[(size_t)e1.x * HD + lane];
            unsigned short y2 = Y[(size_t)e2.x * HD + lane];
            unsigned short y3 = Y[(size_t)e3.x * HD + lane];
            a0 += __int_as_float(e0.y) * bf2f(y0);
            a1 += __int_as_float(e1.y) * bf2f(y1);
            a2 += __int_as_float(e2.y) * bf2f(y2);
            a3 += __int_as_float(e3.y) * bf2f(y3);
            e += 4;
        }
        for (; e < end; ++e) {
            int2 ee = ep[e];
            a0 += __int_as_float(ee.y) * bf2f(Y[(size_t)ee.x * HD + lane]);
        }
    }
    float acc = ((a0 + a1) + (a2 + a3)) + ((a4 + a5) + (a6 + a7));
    if (relu) acc = fmaxf(acc, 0.f);
    if (act) act[((size_t)t * N + d) * HD + lane] = acc;
    if (outp) outp[((size_t)t * N + d) * 192 + lane] = acc;
}

// ---------------- orchestration ----------------

extern "C" void kernel_launch(void* const* d_in, const int* in_sizes, int n_in,
                              void* d_out, int out_size, void* d_ws, size_t ws_size,
                              hipStream_t stream) {
    const float* x0 = (const float*)d_in[0];
    const float* x1 = (const float*)d_in[1];
    const int* src = (const int*)d_in[2];
    const int* dst = (const int*)d_in[3];
    const float* ew = (const float*)d_in[4];
    const float* W1 = (const float*)d_in[5];
    const float* Wl = (const float*)d_in[6];
    float* out = (float*)d_out;

    int N = in_sizes[0] / FD;
    int E = in_sizes[2] / NREL;
    int NBP = idiv_up(N, BUCKET);   // 782 for N=50000 (must be <= 1024 for bscan)

    char* ws = (char*)d_ws;
    size_t off = 0;
    auto alloc = [&](size_t bytes) -> void* {
        void* p = ws + off;
        off = (off + bytes + 255) & ~(size_t)255;
        return p;
    };
    int* bhist   = (int*)alloc((size_t)NREL * NBP * 4);
    int* bptr    = (int*)alloc((size_t)NREL * (NBP + 1) * 4);
    int* gcur    = (int*)alloc((size_t)NREL * NBP * 4);
    int* rowptr  = (int*)alloc((size_t)NREL * (N + 1) * 4);
    int2* edges  = (int2*)alloc((size_t)NREL * E * 8);
    unsigned short* y = (unsigned short*)alloc((size_t)NREL * N * HD * 2);
    float* act   = (float*)alloc((size_t)2 * N * HD * 4);
    int2* staged = (int2*)alloc((size_t)NREL * E * 8);   // dead after bsort
    (void)ws_size;

    // bucket partition + per-bucket counting sort (recomputed every call)
    hipMemsetAsync(bhist, 0, (size_t)NREL * NBP * 4, stream);
    dim3 egrid(idiv_up(E, CHUNK), NREL);
    bhist_kernel<<<egrid, 256, NBP * 4, stream>>>(dst, bhist, E, NBP);
    bscan_kernel<<<NREL, 1024, 0, stream>>>(bhist, bptr, gcur, NBP, E);
    part_kernel<<<egrid, 256, 2 * NBP * 4, stream>>>(src, dst, ew, gcur, staged, E, NBP);
    bsort_kernel<<<dim3(NBP, NREL), 256, 0, stream>>>(staged, bptr, rowptr, edges, E, N, NBP);

    dim3 ggrid(idiv_up(N, 16), NREL);
    dim3 sgrid(idiv_up(N, 4), 2);

    // layer 1: h1 = relu(spmm(x @ W1)); store act + out[:, :, 0:64]
    gemm_kernel<FD><<<ggrid, 256, 0, stream>>>(x0, x1, W1, y, N);
    spmm_kernel<<<sgrid, 256, 0, stream>>>(y, rowptr, edges, act, out + 0, N, E, 1);

    // layers 2..5 with Wl[0..3]
    for (int l = 0; l < 4; ++l) {
        gemm_kernel<HD><<<ggrid, 256, 0, stream>>>(act, act + (size_t)N * HD,
                                                   Wl + (size_t)l * NREL * HD * HD, y, N);
        float* op = (l == 0) ? (out + 64) : (l == 3) ? (out + 128) : nullptr;
        float* ap = (l == 3) ? nullptr : act;
        int relu = (l == 3) ? 0 : 1;
        spmm_kernel<<<sgrid, 256, 0, stream>>>(y, rowptr, edges, ap, op, N, E, relu);
    }
}

// Round 6
// 815.994 us; speedup vs baseline: 7.5972x; 1.0273x over previous
//
#include <hip/hip_runtime.h>
#include <cstddef>

#define NREL 4
#define HD 64
#define FD 128
#define BSHIFT 6
#define BUCKET 64      // nodes per bucket
#define CHUNK 8192     // edges per partition block

static inline int idiv_up(int a, int b) { return (a + b - 1) / b; }

__device__ __forceinline__ unsigned short f2bf(float f) {
    unsigned int u = __float_as_uint(f);
    unsigned int r = (u + 0x7FFFu + ((u >> 16) & 1u)) >> 16;   // RNE
    return (unsigned short)r;
}
__device__ __forceinline__ float bflo(unsigned int v) {
    return __uint_as_float(v << 16);
}
__device__ __forceinline__ float bfhi(unsigned int v) {
    return __uint_as_float(v & 0xFFFF0000u);
}

// ---------------- pass A: per-relation bucket histogram ----------------

__global__ void bhist_kernel(const int* __restrict__ dst, int* __restrict__ bhist,
                             int E, int NBP) {
    int k = blockIdx.y;
    extern __shared__ int lh[];
    for (int i = threadIdx.x; i < NBP; i += blockDim.x) lh[i] = 0;
    __syncthreads();
    const int* dk = dst + (size_t)k * E;
    for (int e = blockIdx.x * blockDim.x + threadIdx.x; e < E; e += gridDim.x * blockDim.x)
        atomicAdd(&lh[dk[e] >> BSHIFT], 1);
    __syncthreads();
    int* bh = bhist + (size_t)k * NBP;
    for (int i = threadIdx.x; i < NBP; i += blockDim.x)
        if (lh[i]) atomicAdd(&bh[i], lh[i]);
}

// ---------------- pass B: exclusive scan of bucket counts (NBP <= 1024) ----------------

__global__ void bscan_kernel(const int* __restrict__ bhist, int* __restrict__ bptr,
                             int* __restrict__ gcur, int NBP, int E) {
    int k = blockIdx.x;
    __shared__ int wsum[16];
    int tid = threadIdx.x, wid = tid >> 6, lane = tid & 63;
    int v = (tid < NBP) ? bhist[(size_t)k * NBP + tid] : 0;
    int x = v;
    #pragma unroll
    for (int off = 1; off < 64; off <<= 1) {
        int y = __shfl_up(x, off, 64);
        if (lane >= off) x += y;
    }
    if (lane == 63) wsum[wid] = x;
    __syncthreads();
    if (wid == 0) {
        int s = (lane < 16) ? wsum[lane] : 0;
        #pragma unroll
        for (int off = 1; off < 16; off <<= 1) {
            int y = __shfl_up(s, off, 64);
            if (lane >= off) s += y;
        }
        if (lane < 16) wsum[lane] = s;
    }
    __syncthreads();
    int excl = x - v + (wid ? wsum[wid - 1] : 0);
    if (tid < NBP) {
        bptr[(size_t)k * (NBP + 1) + tid] = excl;
        gcur[(size_t)k * NBP + tid] = excl;
    }
    if (tid == 0) bptr[(size_t)k * (NBP + 1) + NBP] = E;
}

// ---------------- pass C: block-aggregated bucket partition ----------------
// staged[pos] = { src | (dst_local << 16), bits(w) }, grouped by bucket.

__global__ void part_kernel(const int* __restrict__ src, const int* __restrict__ dst,
                            const float* __restrict__ ew, int* __restrict__ gcur,
                            int2* __restrict__ staged, int E, int NBP) {
    int k = blockIdx.y;
    extern __shared__ int sh[];
    int* lcnt = sh;          // NBP
    int* lbase = sh + NBP;   // NBP
    for (int i = threadIdx.x; i < NBP; i += blockDim.x) lcnt[i] = 0;
    __syncthreads();
    const int* sk = src + (size_t)k * E;
    const int* dk = dst + (size_t)k * E;
    const float* wk = ew + (size_t)k * E;
    int base = blockIdx.x * CHUNK;
    int n = min(CHUNK, E - base);
    for (int i = threadIdx.x; i < n; i += blockDim.x)
        atomicAdd(&lcnt[dk[base + i] >> BSHIFT], 1);
    __syncthreads();
    for (int i = threadIdx.x; i < NBP; i += blockDim.x) {
        int c = lcnt[i];
        lbase[i] = c ? atomicAdd(&gcur[(size_t)k * NBP + i], c) : 0;
    }
    __syncthreads();
    for (int i = threadIdx.x; i < NBP; i += blockDim.x) lcnt[i] = 0;
    __syncthreads();
    int2* out = staged + (size_t)k * E;
    for (int i = threadIdx.x; i < n; i += blockDim.x) {
        int d = dk[base + i];
        int b = d >> BSHIFT;
        int local = atomicAdd(&lcnt[b], 1);
        out[lbase[b] + local] =
            make_int2(sk[base + i] | ((d & (BUCKET - 1)) << 16), __float_as_int(wk[base + i]));
    }
}

// ---------------- pass D: per-bucket LDS counting sort -> node-sorted edges + rowptr ----

__global__ void bsort_kernel(const int2* __restrict__ staged, const int* __restrict__ bptr,
                             int* __restrict__ rowptr, int2* __restrict__ edges,
                             int E, int N, int NBP) {
    int k = blockIdx.y;
    int b = blockIdx.x;
    __shared__ int hist[BUCKET];
    __shared__ int excl[BUCKET];
    __shared__ int cur[BUCKET];
    int tid = threadIdx.x;
    if (tid < BUCKET) hist[tid] = 0;
    __syncthreads();
    int beg = bptr[(size_t)k * (NBP + 1) + b];
    int end = bptr[(size_t)k * (NBP + 1) + b + 1];
    const int2* in = staged + (size_t)k * E;
    for (int i = beg + tid; i < end; i += blockDim.x)
        atomicAdd(&hist[(in[i].x >> 16) & (BUCKET - 1)], 1);
    __syncthreads();
    if (tid < 64) {
        int v = hist[tid];
        int x = v;
        #pragma unroll
        for (int off = 1; off < 64; off <<= 1) {
            int y = __shfl_up(x, off, 64);
            if (tid >= off) x += y;
        }
        excl[tid] = x - v;
        cur[tid] = x - v;
    }
    __syncthreads();
    int2* outp = edges + (size_t)k * E;
    for (int i = beg + tid; i < end; i += blockDim.x) {
        int2 q = in[i];
        int dl = (q.x >> 16) & (BUCKET - 1);
        int pos = atomicAdd(&cur[dl], 1);
        outp[beg + pos] = make_int2(q.x & 0xFFFF, q.y);
    }
    int node0 = b * BUCKET;
    if (tid < BUCKET && node0 + tid < N)
        rowptr[(size_t)k * (N + 1) + node0 + tid] = beg + excl[tid];
    if (b == 0 && tid == 0) rowptr[(size_t)k * (N + 1) + N] = E;
}

// ---------------- Dense GEMM: Y[k] = X_{k%2} @ W_k  (K x 64), bf16 output ----------------

template <int K>
__global__ void gemm_kernel(const float* __restrict__ X0, const float* __restrict__ X1,
                            const float* __restrict__ Wbase, unsigned short* __restrict__ Ybase,
                            int N) {
    __shared__ float sW[K * HD];
    int k = blockIdx.y;
    const float* X = (k & 1) ? X1 : X0;
    const float* W = Wbase + (size_t)k * K * HD;
    unsigned short* Y = Ybase + (size_t)k * N * HD;
    int tid = threadIdx.x;
    for (int i = tid * 4; i < K * HD; i += 256 * 4)
        *reinterpret_cast<float4*>(&sW[i]) = *reinterpret_cast<const float4*>(&W[i]);
    __syncthreads();
    int row = blockIdx.x * 16 + (tid >> 4);
    int col = (tid & 15) * 4;
    if (row >= N) return;
    const float* xr = X + (size_t)row * K;
    float4 acc = {0.f, 0.f, 0.f, 0.f};
    #pragma unroll 8
    for (int kk = 0; kk < K; kk += 4) {
        float4 xv = *reinterpret_cast<const float4*>(xr + kk);
        float4 w0 = *reinterpret_cast<const float4*>(&sW[(kk + 0) * HD + col]);
        float4 w1 = *reinterpret_cast<const float4*>(&sW[(kk + 1) * HD + col]);
        float4 w2 = *reinterpret_cast<const float4*>(&sW[(kk + 2) * HD + col]);
        float4 w3 = *reinterpret_cast<const float4*>(&sW[(kk + 3) * HD + col]);
        acc.x += xv.x * w0.x + xv.y * w1.x + xv.z * w2.x + xv.w * w3.x;
        acc.y += xv.x * w0.y + xv.y * w1.y + xv.z * w2.y + xv.w * w3.y;
        acc.z += xv.x * w0.z + xv.y * w1.z + xv.z * w2.z + xv.w * w3.z;
        acc.w += xv.x * w0.w + xv.y * w1.w + xv.z * w2.w + xv.w * w3.w;
    }
    ushort4 o;
    o.x = f2bf(acc.x); o.y = f2bf(acc.y); o.z = f2bf(acc.z); o.w = f2bf(acc.w);
    *reinterpret_cast<ushort4*>(&Y[(size_t)row * HD + col]) = o;
}

// ---------------- SpMM gather: one wave per dst node ----------------
// Lane layout: h = lane>>5 selects edge parity (2 edges per wave in flight per
// gather instr), c2 = (lane&31)*2 selects a column pair (uint = 2 bf16).
// 4 gathers (8 edges) in flight, edge-metadata prefetched one batch ahead.

__global__ void spmm_kernel(const unsigned short* __restrict__ Ybase,
                            const int* __restrict__ rowptr, const int2* __restrict__ edges,
                            float* __restrict__ act, float* __restrict__ outp,
                            int N, int E, int relu) {
    int t = blockIdx.y;
    int wave = threadIdx.x >> 6;
    int lane = threadIdx.x & 63;
    int d = blockIdx.x * 4 + wave;
    if (d >= N) return;
    int h = lane >> 5;          // which edge of the pair
    int c2 = (lane & 31) * 2;   // column pair
    float2 a0 = {0.f, 0.f}, a1 = {0.f, 0.f}, a2 = {0.f, 0.f}, a3 = {0.f, 0.f};
    #pragma unroll
    for (int rr = 0; rr < 2; ++rr) {
        int r = 2 * t + rr;
        const unsigned short* Y = Ybase + (size_t)r * N * HD;
        const int2* ep = edges + (size_t)r * E;
        int e = rowptr[(size_t)r * (N + 1) + d];
        int end = rowptr[(size_t)r * (N + 1) + d + 1];
        if (e >= end) continue;
        if (e + 8 <= end) {
            int2 m0 = ep[e + 0 + h];
            int2 m1 = ep[e + 2 + h];
            int2 m2 = ep[e + 4 + h];
            int2 m3 = ep[e + 6 + h];
            for (;;) {
                int en = e + 8;
                bool more = (en + 8 <= end);
                int2 n0, n1, n2, n3;
                if (more) {
                    n0 = ep[en + 0 + h];
                    n1 = ep[en + 2 + h];
                    n2 = ep[en + 4 + h];
                    n3 = ep[en + 6 + h];
                }
                unsigned int y0 = *reinterpret_cast<const unsigned int*>(Y + (m0.x * HD + c2));
                unsigned int y1 = *reinterpret_cast<const unsigned int*>(Y + (m1.x * HD + c2));
                unsigned int y2 = *reinterpret_cast<const unsigned int*>(Y + (m2.x * HD + c2));
                unsigned int y3 = *reinterpret_cast<const unsigned int*>(Y + (m3.x * HD + c2));
                float w0 = __int_as_float(m0.y);
                float w1 = __int_as_float(m1.y);
                float w2 = __int_as_float(m2.y);
                float w3 = __int_as_float(m3.y);
                a0.x += w0 * bflo(y0); a0.y += w0 * bfhi(y0);
                a1.x += w1 * bflo(y1); a1.y += w1 * bfhi(y1);
                a2.x += w2 * bflo(y2); a2.y += w2 * bfhi(y2);
                a3.x += w3 * bflo(y3); a3.y += w3 * bfhi(y3);
                e = en;
                if (!more) break;
                m0 = n0; m1 = n1; m2 = n2; m3 = n3;
            }
        }
        // drain (< 8 edges), predicated pair loads
        for (; e < end; e += 2) {
            int idx = e + h;
            int2 q = ep[(idx < end) ? idx : (end - 1)];
            float w = (idx < end) ? __int_as_float(q.y) : 0.f;
            unsigned int yv = *reinterpret_cast<const unsigned int*>(Y + (q.x * HD + c2));
            a0.x += w * bflo(yv); a0.y += w * bfhi(yv);
        }
    }
    float2 s;
    s.x = (a0.x + a1.x) + (a2.x + a3.x);
    s.y = (a0.y + a1.y) + (a2.y + a3.y);
    s.x += __shfl_xor(s.x, 32, 64);
    s.y += __shfl_xor(s.y, 32, 64);
    if (relu) { s.x = fmaxf(s.x, 0.f); s.y = fmaxf(s.y, 0.f); }
    if (lane < 32) {
        if (act) *reinterpret_cast<float2*>(&act[((size_t)t * N + d) * HD + c2]) = s;
        if (outp) *reinterpret_cast<float2*>(&outp[((size_t)t * N + d) * 192 + c2]) = s;
    }
}

// ---------------- orchestration ----------------

extern "C" void kernel_launch(void* const* d_in, const int* in_sizes, int n_in,
                              void* d_out, int out_size, void* d_ws, size_t ws_size,
                              hipStream_t stream) {
    const float* x0 = (const float*)d_in[0];
    const float* x1 = (const float*)d_in[1];
    const int* src = (const int*)d_in[2];
    const int* dst = (const int*)d_in[3];
    const float* ew = (const float*)d_in[4];
    const float* W1 = (const float*)d_in[5];
    const float* Wl = (const float*)d_in[6];
    float* out = (float*)d_out;

    int N = in_sizes[0] / FD;
    int E = in_sizes[2] / NREL;
    int NBP = idiv_up(N, BUCKET);   // 782 for N=50000 (must be <= 1024 for bscan)

    char* ws = (char*)d_ws;
    size_t off = 0;
    auto alloc = [&](size_t bytes) -> void* {
        void* p = ws + off;
        off = (off + bytes + 255) & ~(size_t)255;
        return p;
    };
    int* bhist   = (int*)alloc((size_t)NREL * NBP * 4);
    int* bptr    = (int*)alloc((size_t)NREL * (NBP + 1) * 4);
    int* gcur    = (int*)alloc((size_t)NREL * NBP * 4);
    int* rowptr  = (int*)alloc((size_t)NREL * (N + 1) * 4);
    int2* edges  = (int2*)alloc((size_t)NREL * E * 8);
    unsigned short* y = (unsigned short*)alloc((size_t)NREL * N * HD * 2);
    float* act   = (float*)alloc((size_t)2 * N * HD * 4);
    int2* staged = (int2*)alloc((size_t)NREL * E * 8);   // dead after bsort
    (void)ws_size;

    // bucket partition + per-bucket counting sort (recomputed every call)
    hipMemsetAsync(bhist, 0, (size_t)NREL * NBP * 4, stream);
    dim3 egrid(idiv_up(E, CHUNK), NREL);
    bhist_kernel<<<egrid, 256, NBP * 4, stream>>>(dst, bhist, E, NBP);
    bscan_kernel<<<NREL, 1024, 0, stream>>>(bhist, bptr, gcur, NBP, E);
    part_kernel<<<egrid, 256, 2 * NBP * 4, stream>>>(src, dst, ew, gcur, staged, E, NBP);
    bsort_kernel<<<dim3(NBP, NREL), 256, 0, stream>>>(staged, bptr, rowptr, edges, E, N, NBP);

    dim3 ggrid(idiv_up(N, 16), NREL);
    dim3 sgrid(idiv_up(N, 4), 2);

    // layer 1: h1 = relu(spmm(x @ W1)); store act + out[:, :, 0:64]
    gemm_kernel<FD><<<ggrid, 256, 0, stream>>>(x0, x1, W1, y, N);
    spmm_kernel<<<sgrid, 256, 0, stream>>>(y, rowptr, edges, act, out + 0, N, E, 1);

    // layers 2..5 with Wl[0..3]
    for (int l = 0; l < 4; ++l) {
        gemm_kernel<HD><<<ggrid, 256, 0, stream>>>(act, act + (size_t)N * HD,
                                                   Wl + (size_t)l * NREL * HD * HD, y, N);
        float* op = (l == 0) ? (out + 64) : (l == 3) ? (out + 128) : nullptr;
        float* ap = (l == 3) ? nullptr : act;
        int relu = (l == 3) ? 0 : 1;
        spmm_kernel<<<sgrid, 256, 0, stream>>>(y, rowptr, edges, ap, op, N, E, relu);
    }
}

// Round 7
// 672.191 us; speedup vs baseline: 9.2225x; 1.2139x over previous
//
#include <hip/hip_runtime.h>
#include <cstddef>

#define NREL 4
#define HD 64
#define FD 128
#define BSHIFT 6
#define BUCKET 64      // nodes per bucket
#define CHUNK 8192     // edges per partition block

static inline int idiv_up(int a, int b) { return (a + b - 1) / b; }

typedef __attribute__((ext_vector_type(8))) short bf16x8;
typedef __attribute__((ext_vector_type(4))) float f32x4;

__device__ __forceinline__ unsigned short f2bf(float f) {
    unsigned int u = __float_as_uint(f);
    unsigned int r = (u + 0x7FFFu + ((u >> 16) & 1u)) >> 16;   // RNE
    return (unsigned short)r;
}
__device__ __forceinline__ float bflo(unsigned int v) {
    return __uint_as_float(v << 16);
}
__device__ __forceinline__ float bfhi(unsigned int v) {
    return __uint_as_float(v & 0xFFFF0000u);
}

// ---------------- pass A: per-relation bucket histogram ----------------

__global__ void bhist_kernel(const int* __restrict__ dst, int* __restrict__ bhist,
                             int E, int NBP) {
    int k = blockIdx.y;
    extern __shared__ int lh[];
    for (int i = threadIdx.x; i < NBP; i += blockDim.x) lh[i] = 0;
    __syncthreads();
    const int* dk = dst + (size_t)k * E;
    for (int e = blockIdx.x * blockDim.x + threadIdx.x; e < E; e += gridDim.x * blockDim.x)
        atomicAdd(&lh[dk[e] >> BSHIFT], 1);
    __syncthreads();
    int* bh = bhist + (size_t)k * NBP;
    for (int i = threadIdx.x; i < NBP; i += blockDim.x)
        if (lh[i]) atomicAdd(&bh[i], lh[i]);
}

// ---------------- pass B: exclusive scan of bucket counts (NBP <= 1024) ----------------

__global__ void bscan_kernel(const int* __restrict__ bhist, int* __restrict__ bptr,
                             int* __restrict__ gcur, int NBP, int E) {
    int k = blockIdx.x;
    __shared__ int wsum[16];
    int tid = threadIdx.x, wid = tid >> 6, lane = tid & 63;
    int v = (tid < NBP) ? bhist[(size_t)k * NBP + tid] : 0;
    int x = v;
    #pragma unroll
    for (int off = 1; off < 64; off <<= 1) {
        int y = __shfl_up(x, off, 64);
        if (lane >= off) x += y;
    }
    if (lane == 63) wsum[wid] = x;
    __syncthreads();
    if (wid == 0) {
        int s = (lane < 16) ? wsum[lane] : 0;
        #pragma unroll
        for (int off = 1; off < 16; off <<= 1) {
            int y = __shfl_up(s, off, 64);
            if (lane >= off) s += y;
        }
        if (lane < 16) wsum[lane] = s;
    }
    __syncthreads();
    int excl = x - v + (wid ? wsum[wid - 1] : 0);
    if (tid < NBP) {
        bptr[(size_t)k * (NBP + 1) + tid] = excl;
        gcur[(size_t)k * NBP + tid] = excl;
    }
    if (tid == 0) bptr[(size_t)k * (NBP + 1) + NBP] = E;
}

// ---------------- pass C: block-aggregated bucket partition ----------------

__global__ void part_kernel(const int* __restrict__ src, const int* __restrict__ dst,
                            const float* __restrict__ ew, int* __restrict__ gcur,
                            int2* __restrict__ staged, int E, int NBP) {
    int k = blockIdx.y;
    extern __shared__ int sh[];
    int* lcnt = sh;          // NBP
    int* lbase = sh + NBP;   // NBP
    for (int i = threadIdx.x; i < NBP; i += blockDim.x) lcnt[i] = 0;
    __syncthreads();
    const int* sk = src + (size_t)k * E;
    const int* dk = dst + (size_t)k * E;
    const float* wk = ew + (size_t)k * E;
    int base = blockIdx.x * CHUNK;
    int n = min(CHUNK, E - base);
    for (int i = threadIdx.x; i < n; i += blockDim.x)
        atomicAdd(&lcnt[dk[base + i] >> BSHIFT], 1);
    __syncthreads();
    for (int i = threadIdx.x; i < NBP; i += blockDim.x) {
        int c = lcnt[i];
        lbase[i] = c ? atomicAdd(&gcur[(size_t)k * NBP + i], c) : 0;
    }
    __syncthreads();
    for (int i = threadIdx.x; i < NBP; i += blockDim.x) lcnt[i] = 0;
    __syncthreads();
    int2* out = staged + (size_t)k * E;
    for (int i = threadIdx.x; i < n; i += blockDim.x) {
        int d = dk[base + i];
        int b = d >> BSHIFT;
        int local = atomicAdd(&lcnt[b], 1);
        out[lbase[b] + local] =
            make_int2(sk[base + i] | ((d & (BUCKET - 1)) << 16), __float_as_int(wk[base + i]));
    }
}

// ---------------- pass D: per-bucket LDS counting sort -> node-sorted edges + rowptr ----

__global__ void bsort_kernel(const int2* __restrict__ staged, const int* __restrict__ bptr,
                             int* __restrict__ rowptr, int2* __restrict__ edges,
                             int E, int N, int NBP) {
    int k = blockIdx.y;
    int b = blockIdx.x;
    __shared__ int hist[BUCKET];
    __shared__ int excl[BUCKET];
    __shared__ int cur[BUCKET];
    int tid = threadIdx.x;
    if (tid < BUCKET) hist[tid] = 0;
    __syncthreads();
    int beg = bptr[(size_t)k * (NBP + 1) + b];
    int end = bptr[(size_t)k * (NBP + 1) + b + 1];
    const int2* in = staged + (size_t)k * E;
    for (int i = beg + tid; i < end; i += blockDim.x)
        atomicAdd(&hist[(in[i].x >> 16) & (BUCKET - 1)], 1);
    __syncthreads();
    if (tid < 64) {
        int v = hist[tid];
        int x = v;
        #pragma unroll
        for (int off = 1; off < 64; off <<= 1) {
            int y = __shfl_up(x, off, 64);
            if (tid >= off) x += y;
        }
        excl[tid] = x - v;
        cur[tid] = x - v;
    }
    __syncthreads();
    int2* outp = edges + (size_t)k * E;
    for (int i = beg + tid; i < end; i += blockDim.x) {
        int2 q = in[i];
        int dl = (q.x >> 16) & (BUCKET - 1);
        int pos = atomicAdd(&cur[dl], 1);
        outp[beg + pos] = make_int2(q.x & 0xFFFF, q.y);
    }
    int node0 = b * BUCKET;
    if (tid < BUCKET && node0 + tid < N)
        rowptr[(size_t)k * (N + 1) + node0 + tid] = beg + excl[tid];
    if (b == 0 && tid == 0) rowptr[(size_t)k * (N + 1) + N] = E;
}

// ---------------- converts: x -> bf16, W -> bf16 fragment-swizzled ----------------

__global__ void convx_kernel(const float* __restrict__ x0, const float* __restrict__ x1,
                             unsigned short* __restrict__ xb, int nq /* quads per array */) {
    for (int i = blockIdx.x * blockDim.x + threadIdx.x; i < 2 * nq;
         i += gridDim.x * blockDim.x) {
        const float4* xs = (i < nq) ? (const float4*)x0 : (const float4*)x1;
        int j = (i < nq) ? i : i - nq;
        float4 v = xs[j];
        ushort4 o;
        o.x = f2bf(v.x); o.y = f2bf(v.y); o.z = f2bf(v.z); o.w = f2bf(v.w);
        reinterpret_cast<ushort4*>(xb)[i] = o;
    }
}

// Wf[mat][kk][n][lane][i] = W[mat][kk*32 + (lane>>4)*8 + i][n*16 + (lane&15)]
__global__ void convw_kernel(const float* __restrict__ W, unsigned short* __restrict__ Wf,
                             int mats, int KK) {
    int tid = blockIdx.x * blockDim.x + threadIdx.x;
    int total = mats * KK * 4 * 64;
    if (tid >= total) return;
    int l = tid & 63;
    int n = (tid >> 6) & 3;
    int rest = tid >> 8;
    int kk = rest % KK;
    int mat = rest / KK;
    int h = l >> 4, c = l & 15;
    int K = KK * 32;
    const float* Wm = W + (size_t)mat * K * 64;
    unsigned short* o = Wf + (size_t)tid * 8;
    #pragma unroll
    for (int i = 0; i < 8; ++i)
        o[i] = f2bf(Wm[(size_t)(kk * 32 + h * 8 + i) * 64 + n * 16 + c]);
}

// ---------------- MFMA GEMM: Y[rel] = X_{rel%2} @ W_rel, bf16 in/out, f32 acc ----------

template <int K>
__global__ void gemm_mfma_kernel(const unsigned short* __restrict__ Xb,
                                 const unsigned short* __restrict__ Wf,
                                 unsigned short* __restrict__ Ybase, int N) {
    constexpr int KK = K / 32;
    int rel = blockIdx.y;
    const unsigned short* X = Xb + (size_t)(rel & 1) * N * K;
    const bf16x8* Wv = reinterpret_cast<const bf16x8*>(Wf + (size_t)rel * KK * 4 * 64 * 8);
    unsigned short* Y = Ybase + (size_t)rel * N * HD;
    int tid = threadIdx.x;
    int w = tid >> 6, l = tid & 63;
    int lr = l & 15, lh = l >> 4;
    int row0 = blockIdx.x * 128 + w * 32;
    f32x4 acc00 = {0.f,0.f,0.f,0.f}, acc01 = {0.f,0.f,0.f,0.f};
    f32x4 acc02 = {0.f,0.f,0.f,0.f}, acc03 = {0.f,0.f,0.f,0.f};
    f32x4 acc10 = {0.f,0.f,0.f,0.f}, acc11 = {0.f,0.f,0.f,0.f};
    f32x4 acc12 = {0.f,0.f,0.f,0.f}, acc13 = {0.f,0.f,0.f,0.f};
    int r0 = min(row0 + lr, N - 1);
    int r1 = min(row0 + 16 + lr, N - 1);
    const unsigned short* xp0 = X + (size_t)r0 * K + lh * 8;
    const unsigned short* xp1 = X + (size_t)r1 * K + lh * 8;
    #pragma unroll
    for (int kk = 0; kk < KK; ++kk) {
        bf16x8 a0 = *reinterpret_cast<const bf16x8*>(xp0 + kk * 32);
        bf16x8 a1 = *reinterpret_cast<const bf16x8*>(xp1 + kk * 32);
        bf16x8 b0 = Wv[(kk * 4 + 0) * 64 + l];
        bf16x8 b1 = Wv[(kk * 4 + 1) * 64 + l];
        bf16x8 b2 = Wv[(kk * 4 + 2) * 64 + l];
        bf16x8 b3 = Wv[(kk * 4 + 3) * 64 + l];
        acc00 = __builtin_amdgcn_mfma_f32_16x16x32_bf16(a0, b0, acc00, 0, 0, 0);
        acc01 = __builtin_amdgcn_mfma_f32_16x16x32_bf16(a0, b1, acc01, 0, 0, 0);
        acc02 = __builtin_amdgcn_mfma_f32_16x16x32_bf16(a0, b2, acc02, 0, 0, 0);
        acc03 = __builtin_amdgcn_mfma_f32_16x16x32_bf16(a0, b3, acc03, 0, 0, 0);
        acc10 = __builtin_amdgcn_mfma_f32_16x16x32_bf16(a1, b0, acc10, 0, 0, 0);
        acc11 = __builtin_amdgcn_mfma_f32_16x16x32_bf16(a1, b1, acc11, 0, 0, 0);
        acc12 = __builtin_amdgcn_mfma_f32_16x16x32_bf16(a1, b2, acc12, 0, 0, 0);
        acc13 = __builtin_amdgcn_mfma_f32_16x16x32_bf16(a1, b3, acc13, 0, 0, 0);
    }
    // C/D layout: col = lane&15, row(in tile) = (lane>>4)*4 + reg  [HW-verified]
    #pragma unroll
    for (int reg = 0; reg < 4; ++reg) {
        int rowa = row0 + lh * 4 + reg;
        if (rowa < N) {
            unsigned short* yp = Y + (size_t)rowa * HD + lr;
            yp[0]  = f2bf(acc00[reg]);
            yp[16] = f2bf(acc01[reg]);
            yp[32] = f2bf(acc02[reg]);
            yp[48] = f2bf(acc03[reg]);
        }
        int rowb = row0 + 16 + lh * 4 + reg;
        if (rowb < N) {
            unsigned short* yp = Y + (size_t)rowb * HD + lr;
            yp[0]  = f2bf(acc10[reg]);
            yp[16] = f2bf(acc11[reg]);
            yp[32] = f2bf(acc12[reg]);
            yp[48] = f2bf(acc13[reg]);
        }
    }
}

// ---------------- SpMM gather: one wave per dst node ----------------
// h = lane>>5 edge parity, c2 = (lane&31)*2 column pair; act out bf16, out f32.

__global__ void spmm_kernel(const unsigned short* __restrict__ Ybase,
                            const int* __restrict__ rowptr, const int2* __restrict__ edges,
                            unsigned short* __restrict__ act, float* __restrict__ outp,
                            int N, int E, int relu) {
    int t = blockIdx.y;
    int wave = threadIdx.x >> 6;
    int lane = threadIdx.x & 63;
    int d = blockIdx.x * 4 + wave;
    if (d >= N) return;
    int h = lane >> 5;
    int c2 = (lane & 31) * 2;
    float2 a0 = {0.f, 0.f}, a1 = {0.f, 0.f}, a2 = {0.f, 0.f}, a3 = {0.f, 0.f};
    #pragma unroll
    for (int rr = 0; rr < 2; ++rr) {
        int r = 2 * t + rr;
        const unsigned short* Y = Ybase + (size_t)r * N * HD;
        const int2* ep = edges + (size_t)r * E;
        int e = rowptr[(size_t)r * (N + 1) + d];
        int end = rowptr[(size_t)r * (N + 1) + d + 1];
        if (e >= end) continue;
        if (e + 8 <= end) {
            int2 m0 = ep[e + 0 + h];
            int2 m1 = ep[e + 2 + h];
            int2 m2 = ep[e + 4 + h];
            int2 m3 = ep[e + 6 + h];
            for (;;) {
                int en = e + 8;
                bool more = (en + 8 <= end);
                int2 n0, n1, n2, n3;
                if (more) {
                    n0 = ep[en + 0 + h];
                    n1 = ep[en + 2 + h];
                    n2 = ep[en + 4 + h];
                    n3 = ep[en + 6 + h];
                }
                unsigned int y0 = *reinterpret_cast<const unsigned int*>(Y + (m0.x * HD + c2));
                unsigned int y1 = *reinterpret_cast<const unsigned int*>(Y + (m1.x * HD + c2));
                unsigned int y2 = *reinterpret_cast<const unsigned int*>(Y + (m2.x * HD + c2));
                unsigned int y3 = *reinterpret_cast<const unsigned int*>(Y + (m3.x * HD + c2));
                float w0 = __int_as_float(m0.y);
                float w1 = __int_as_float(m1.y);
                float w2 = __int_as_float(m2.y);
                float w3 = __int_as_float(m3.y);
                a0.x += w0 * bflo(y0); a0.y += w0 * bfhi(y0);
                a1.x += w1 * bflo(y1); a1.y += w1 * bfhi(y1);
                a2.x += w2 * bflo(y2); a2.y += w2 * bfhi(y2);
                a3.x += w3 * bflo(y3); a3.y += w3 * bfhi(y3);
                e = en;
                if (!more) break;
                m0 = n0; m1 = n1; m2 = n2; m3 = n3;
            }
        }
        for (; e < end; e += 2) {
            int idx = e + h;
            int2 q = ep[(idx < end) ? idx : (end - 1)];
            float w = (idx < end) ? __int_as_float(q.y) : 0.f;
            unsigned int yv = *reinterpret_cast<const unsigned int*>(Y + (q.x * HD + c2));
            a0.x += w * bflo(yv); a0.y += w * bfhi(yv);
        }
    }
    float2 s;
    s.x = (a0.x + a1.x) + (a2.x + a3.x);
    s.y = (a0.y + a1.y) + (a2.y + a3.y);
    s.x += __shfl_xor(s.x, 32, 64);
    s.y += __shfl_xor(s.y, 32, 64);
    if (relu) { s.x = fmaxf(s.x, 0.f); s.y = fmaxf(s.y, 0.f); }
    if (lane < 32) {
        if (act) {
            ushort2 ob; ob.x = f2bf(s.x); ob.y = f2bf(s.y);
            *reinterpret_cast<ushort2*>(&act[((size_t)t * N + d) * HD + c2]) = ob;
        }
        if (outp) *reinterpret_cast<float2*>(&outp[((size_t)t * N + d) * 192 + c2]) = s;
    }
}

// ---------------- orchestration ----------------

extern "C" void kernel_launch(void* const* d_in, const int* in_sizes, int n_in,
                              void* d_out, int out_size, void* d_ws, size_t ws_size,
                              hipStream_t stream) {
    const float* x0 = (const float*)d_in[0];
    const float* x1 = (const float*)d_in[1];
    const int* src = (const int*)d_in[2];
    const int* dst = (const int*)d_in[3];
    const float* ew = (const float*)d_in[4];
    const float* W1 = (const float*)d_in[5];
    const float* Wl = (const float*)d_in[6];
    float* out = (float*)d_out;

    int N = in_sizes[0] / FD;
    int E = in_sizes[2] / NREL;
    int NBP = idiv_up(N, BUCKET);   // 782 for N=50000 (must be <= 1024 for bscan)

    char* ws = (char*)d_ws;
    size_t off = 0;
    auto alloc = [&](size_t bytes) -> void* {
        void* p = ws + off;
        off = (off + bytes + 255) & ~(size_t)255;
        return p;
    };
    int* bhist   = (int*)alloc((size_t)NREL * NBP * 4);
    int* bptr    = (int*)alloc((size_t)NREL * (NBP + 1) * 4);
    int* gcur    = (int*)alloc((size_t)NREL * NBP * 4);
    int* rowptr  = (int*)alloc((size_t)NREL * (N + 1) * 4);
    int2* edges  = (int2*)alloc((size_t)NREL * E * 8);
    unsigned short* y    = (unsigned short*)alloc((size_t)NREL * N * HD * 2);
    unsigned short* xb   = (unsigned short*)alloc((size_t)2 * N * FD * 2);
    unsigned short* actb = (unsigned short*)alloc((size_t)2 * N * HD * 2);
    unsigned short* W1f  = (unsigned short*)alloc((size_t)NREL * 4 * 4 * 64 * 8 * 2);
    unsigned short* Wlf  = (unsigned short*)alloc((size_t)16 * 2 * 4 * 64 * 8 * 2);
    int2* staged = (int2*)alloc((size_t)NREL * E * 8);   // dead after bsort
    (void)ws_size;

    // input converts
    int nq = N * FD / 4;
    convx_kernel<<<2048, 256, 0, stream>>>(x0, x1, xb, nq);
    convw_kernel<<<idiv_up(NREL * 4 * 4 * 64, 256), 256, 0, stream>>>(W1, W1f, NREL, 4);
    convw_kernel<<<idiv_up(16 * 2 * 4 * 64, 256), 256, 0, stream>>>(Wl, Wlf, 16, 2);

    // bucket partition + per-bucket counting sort (recomputed every call)
    hipMemsetAsync(bhist, 0, (size_t)NREL * NBP * 4, stream);
    dim3 egrid(idiv_up(E, CHUNK), NREL);
    bhist_kernel<<<egrid, 256, NBP * 4, stream>>>(dst, bhist, E, NBP);
    bscan_kernel<<<NREL, 1024, 0, stream>>>(bhist, bptr, gcur, NBP, E);
    part_kernel<<<egrid, 256, 2 * NBP * 4, stream>>>(src, dst, ew, gcur, staged, E, NBP);
    bsort_kernel<<<dim3(NBP, NREL), 256, 0, stream>>>(staged, bptr, rowptr, edges, E, N, NBP);

    dim3 ggrid(idiv_up(N, 128), NREL);
    dim3 sgrid(idiv_up(N, 4), 2);

    // layer 1: h1 = relu(spmm(x @ W1)); store act(bf16) + out[:, :, 0:64]
    gemm_mfma_kernel<FD><<<ggrid, 256, 0, stream>>>(xb, W1f, y, N);
    spmm_kernel<<<sgrid, 256, 0, stream>>>(y, rowptr, edges, actb, out + 0, N, E, 1);

    // layers 2..5 with Wl[0..3]
    for (int l = 0; l < 4; ++l) {
        gemm_mfma_kernel<HD><<<ggrid, 256, 0, stream>>>(
            actb, Wlf + (size_t)l * 4 * 2 * 4 * 64 * 8, y, N);
        float* op = (l == 0) ? (out + 64) : (l == 3) ? (out + 128) : nullptr;
        unsigned short* ap = (l == 3) ? nullptr : actb;
        int relu = (l == 3) ? 0 : 1;
        spmm_kernel<<<sgrid, 256, 0, stream>>>(y, rowptr, edges, ap, op, N, E, relu);
    }
}

// Round 8
// 511.742 us; speedup vs baseline: 12.1140x; 1.3135x over previous
//
#include <hip/hip_runtime.h>
#include <cstddef>

#define NREL 4
#define NSUP 2         // super-relations (pairs of relations sharing a dst type)
#define HD 64
#define FD 128
#define BSHIFT 6
#define BUCKET 64      // nodes per bucket
#define CHUNK 8192     // edges per partition block

static inline int idiv_up(int a, int b) { return (a + b - 1) / b; }

typedef __attribute__((ext_vector_type(8))) short bf16x8;
typedef __attribute__((ext_vector_type(4))) float f32x4;

__device__ __forceinline__ unsigned short f2bf(float f) {
    unsigned int u = __float_as_uint(f);
    unsigned int r = (u + 0x7FFFu + ((u >> 16) & 1u)) >> 16;   // RNE
    return (unsigned short)r;
}
__device__ __forceinline__ float bflo(unsigned int v) {
    return __uint_as_float(v << 16);
}
__device__ __forceinline__ float bfhi(unsigned int v) {
    return __uint_as_float(v & 0xFFFF0000u);
}

// ---------------- pass A: per-super-relation bucket histogram ----------------

__global__ void bhist_kernel(const int* __restrict__ dst, int* __restrict__ bhist,
                             int E2, int NBP) {
    int k = blockIdx.y;
    extern __shared__ int lh[];
    for (int i = threadIdx.x; i < NBP; i += blockDim.x) lh[i] = 0;
    __syncthreads();
    const int* dk = dst + (size_t)k * E2;
    for (int e = blockIdx.x * blockDim.x + threadIdx.x; e < E2; e += gridDim.x * blockDim.x)
        atomicAdd(&lh[dk[e] >> BSHIFT], 1);
    __syncthreads();
    int* bh = bhist + (size_t)k * NBP;
    for (int i = threadIdx.x; i < NBP; i += blockDim.x)
        if (lh[i]) atomicAdd(&bh[i], lh[i]);
}

// ---------------- pass B: exclusive scan of bucket counts (NBP <= 1024) ----------------

__global__ void bscan_kernel(const int* __restrict__ bhist, int* __restrict__ bptr,
                             int* __restrict__ gcur, int NBP, int E2) {
    int k = blockIdx.x;
    __shared__ int wsum[16];
    int tid = threadIdx.x, wid = tid >> 6, lane = tid & 63;
    int v = (tid < NBP) ? bhist[(size_t)k * NBP + tid] : 0;
    int x = v;
    #pragma unroll
    for (int off = 1; off < 64; off <<= 1) {
        int y = __shfl_up(x, off, 64);
        if (lane >= off) x += y;
    }
    if (lane == 63) wsum[wid] = x;
    __syncthreads();
    if (wid == 0) {
        int s = (lane < 16) ? wsum[lane] : 0;
        #pragma unroll
        for (int off = 1; off < 16; off <<= 1) {
            int y = __shfl_up(s, off, 64);
            if (lane >= off) s += y;
        }
        if (lane < 16) wsum[lane] = s;
    }
    __syncthreads();
    int excl = x - v + (wid ? wsum[wid - 1] : 0);
    if (tid < NBP) {
        bptr[(size_t)k * (NBP + 1) + tid] = excl;
        gcur[(size_t)k * NBP + tid] = excl;
    }
    if (tid == 0) bptr[(size_t)k * (NBP + 1) + NBP] = E2;
}

// ---------------- pass C: block-aggregated bucket partition ----------------
// staged[pos] = { row17 | (dst_local6 << 17), bits(w) }, grouped by dst bucket.
// row = src + N * (edge belongs to 2nd relation of the pair).

__global__ void part_kernel(const int* __restrict__ src, const int* __restrict__ dst,
                            const float* __restrict__ ew, int* __restrict__ gcur,
                            int2* __restrict__ staged, int E, int E2, int N, int NBP) {
    int k = blockIdx.y;
    extern __shared__ int sh[];
    int* lcnt = sh;          // NBP
    int* lbase = sh + NBP;   // NBP
    for (int i = threadIdx.x; i < NBP; i += blockDim.x) lcnt[i] = 0;
    __syncthreads();
    const int* sk = src + (size_t)k * E2;
    const int* dk = dst + (size_t)k * E2;
    const float* wk = ew + (size_t)k * E2;
    int base = blockIdx.x * CHUNK;
    int n = min(CHUNK, E2 - base);
    for (int i = threadIdx.x; i < n; i += blockDim.x)
        atomicAdd(&lcnt[dk[base + i] >> BSHIFT], 1);
    __syncthreads();
    for (int i = threadIdx.x; i < NBP; i += blockDim.x) {
        int c = lcnt[i];
        lbase[i] = c ? atomicAdd(&gcur[(size_t)k * NBP + i], c) : 0;
    }
    __syncthreads();
    for (int i = threadIdx.x; i < NBP; i += blockDim.x) lcnt[i] = 0;
    __syncthreads();
    int2* out = staged + (size_t)k * E2;
    for (int i = threadIdx.x; i < n; i += blockDim.x) {
        int gi = base + i;
        int d = dk[gi];
        int b = d >> BSHIFT;
        int row = sk[gi] + ((gi >= E) ? N : 0);
        int local = atomicAdd(&lcnt[b], 1);
        out[lbase[b] + local] =
            make_int2(row | ((d & (BUCKET - 1)) << 17), __float_as_int(wk[gi]));
    }
}

// ---------------- pass D: per-bucket LDS counting sort -> node-sorted 4B edges + rowptr --

__global__ void bsort_kernel(const int2* __restrict__ staged, const int* __restrict__ bptr,
                             int* __restrict__ rowptr, unsigned int* __restrict__ edges,
                             int E2, int N, int NBP) {
    int k = blockIdx.y;
    int b = blockIdx.x;
    __shared__ int hist[BUCKET];
    __shared__ int excl[BUCKET];
    __shared__ int cur[BUCKET];
    int tid = threadIdx.x;
    if (tid < BUCKET) hist[tid] = 0;
    __syncthreads();
    int beg = bptr[(size_t)k * (NBP + 1) + b];
    int end = bptr[(size_t)k * (NBP + 1) + b + 1];
    const int2* in = staged + (size_t)k * E2;
    for (int i = beg + tid; i < end; i += blockDim.x)
        atomicAdd(&hist[(in[i].x >> 17) & (BUCKET - 1)], 1);
    __syncthreads();
    if (tid < 64) {
        int v = hist[tid];
        int x = v;
        #pragma unroll
        for (int off = 1; off < 64; off <<= 1) {
            int y = __shfl_up(x, off, 64);
            if (tid >= off) x += y;
        }
        excl[tid] = x - v;
        cur[tid] = x - v;
    }
    __syncthreads();
    unsigned int* outp = edges + (size_t)k * E2;
    for (int i = beg + tid; i < end; i += blockDim.x) {
        int2 q = in[i];
        int dl = (q.x >> 17) & (BUCKET - 1);
        int pos = atomicAdd(&cur[dl], 1);
        unsigned int wb = (unsigned int)(f2bf(__int_as_float(q.y)) & 0x7FFF);
        outp[beg + pos] = ((unsigned int)q.x & 0x1FFFFu) | (wb << 17);
    }
    int node0 = b * BUCKET;
    if (tid < BUCKET && node0 + tid < N)
        rowptr[(size_t)k * (N + 1) + node0 + tid] = beg + excl[tid];
    if (b == 0 && tid == 0) rowptr[(size_t)k * (N + 1) + N] = E2;
}

// ---------------- converts: x -> bf16, W -> bf16 fragment-swizzled ----------------

__global__ void convx_kernel(const float* __restrict__ x0, const float* __restrict__ x1,
                             unsigned short* __restrict__ xb, int nq /* quads per array */) {
    for (int i = blockIdx.x * blockDim.x + threadIdx.x; i < 2 * nq;
         i += gridDim.x * blockDim.x) {
        const float4* xs = (i < nq) ? (const float4*)x0 : (const float4*)x1;
        int j = (i < nq) ? i : i - nq;
        float4 v = xs[j];
        ushort4 o;
        o.x = f2bf(v.x); o.y = f2bf(v.y); o.z = f2bf(v.z); o.w = f2bf(v.w);
        reinterpret_cast<ushort4*>(xb)[i] = o;
    }
}

// Wf[mat][kk][n][lane][i] = W[mat][kk*32 + (lane>>4)*8 + i][n*16 + (lane&15)]
__global__ void convw_kernel(const float* __restrict__ W, unsigned short* __restrict__ Wf,
                             int mats, int KK) {
    int tid = blockIdx.x * blockDim.x + threadIdx.x;
    int total = mats * KK * 4 * 64;
    if (tid >= total) return;
    int l = tid & 63;
    int n = (tid >> 6) & 3;
    int rest = tid >> 8;
    int kk = rest % KK;
    int mat = rest / KK;
    int h = l >> 4, c = l & 15;
    int K = KK * 32;
    const float* Wm = W + (size_t)mat * K * 64;
    unsigned short* o = Wf + (size_t)tid * 8;
    #pragma unroll
    for (int i = 0; i < 8; ++i)
        o[i] = f2bf(Wm[(size_t)(kk * 32 + h * 8 + i) * 64 + n * 16 + c]);
}

// ---------------- MFMA GEMM: Y[rel] = X_{rel%2} @ W_rel, bf16 in/out, f32 acc ----------

template <int K>
__global__ void gemm_mfma_kernel(const unsigned short* __restrict__ Xb,
                                 const unsigned short* __restrict__ Wf,
                                 unsigned short* __restrict__ Ybase, int N) {
    constexpr int KK = K / 32;
    int rel = blockIdx.y;
    const unsigned short* X = Xb + (size_t)(rel & 1) * N * K;
    const bf16x8* Wv = reinterpret_cast<const bf16x8*>(Wf + (size_t)rel * KK * 4 * 64 * 8);
    unsigned short* Y = Ybase + (size_t)rel * N * HD;
    int tid = threadIdx.x;
    int w = tid >> 6, l = tid & 63;
    int lr = l & 15, lh = l >> 4;
    int row0 = blockIdx.x * 128 + w * 32;
    f32x4 acc00 = {0.f,0.f,0.f,0.f}, acc01 = {0.f,0.f,0.f,0.f};
    f32x4 acc02 = {0.f,0.f,0.f,0.f}, acc03 = {0.f,0.f,0.f,0.f};
    f32x4 acc10 = {0.f,0.f,0.f,0.f}, acc11 = {0.f,0.f,0.f,0.f};
    f32x4 acc12 = {0.f,0.f,0.f,0.f}, acc13 = {0.f,0.f,0.f,0.f};
    int r0 = min(row0 + lr, N - 1);
    int r1 = min(row0 + 16 + lr, N - 1);
    const unsigned short* xp0 = X + (size_t)r0 * K + lh * 8;
    const unsigned short* xp1 = X + (size_t)r1 * K + lh * 8;
    #pragma unroll
    for (int kk = 0; kk < KK; ++kk) {
        bf16x8 a0 = *reinterpret_cast<const bf16x8*>(xp0 + kk * 32);
        bf16x8 a1 = *reinterpret_cast<const bf16x8*>(xp1 + kk * 32);
        bf16x8 b0 = Wv[(kk * 4 + 0) * 64 + l];
        bf16x8 b1 = Wv[(kk * 4 + 1) * 64 + l];
        bf16x8 b2 = Wv[(kk * 4 + 2) * 64 + l];
        bf16x8 b3 = Wv[(kk * 4 + 3) * 64 + l];
        acc00 = __builtin_amdgcn_mfma_f32_16x16x32_bf16(a0, b0, acc00, 0, 0, 0);
        acc01 = __builtin_amdgcn_mfma_f32_16x16x32_bf16(a0, b1, acc01, 0, 0, 0);
        acc02 = __builtin_amdgcn_mfma_f32_16x16x32_bf16(a0, b2, acc02, 0, 0, 0);
        acc03 = __builtin_amdgcn_mfma_f32_16x16x32_bf16(a0, b3, acc03, 0, 0, 0);
        acc10 = __builtin_amdgcn_mfma_f32_16x16x32_bf16(a1, b0, acc10, 0, 0, 0);
        acc11 = __builtin_amdgcn_mfma_f32_16x16x32_bf16(a1, b1, acc11, 0, 0, 0);
        acc12 = __builtin_amdgcn_mfma_f32_16x16x32_bf16(a1, b2, acc12, 0, 0, 0);
        acc13 = __builtin_amdgcn_mfma_f32_16x16x32_bf16(a1, b3, acc13, 0, 0, 0);
    }
    // C/D layout: col = lane&15, row(in tile) = (lane>>4)*4 + reg  [HW-verified]
    #pragma unroll
    for (int reg = 0; reg < 4; ++reg) {
        int rowa = row0 + lh * 4 + reg;
        if (rowa < N) {
            unsigned short* yp = Y + (size_t)rowa * HD + lr;
            yp[0]  = f2bf(acc00[reg]);
            yp[16] = f2bf(acc01[reg]);
            yp[32] = f2bf(acc02[reg]);
            yp[48] = f2bf(acc03[reg]);
        }
        int rowb = row0 + 16 + lh * 4 + reg;
        if (rowb < N) {
            unsigned short* yp = Y + (size_t)rowb * HD + lr;
            yp[0]  = f2bf(acc10[reg]);
            yp[16] = f2bf(acc11[reg]);
            yp[32] = f2bf(acc12[reg]);
            yp[48] = f2bf(acc13[reg]);
        }
    }
}

// ---------------- SpMM gather: one wave per dst node, combined relation pair ----------
// edge rec: row17 | wbf15<<17 (row < 2N indexes the contiguous y pair for this type).
// h = lane>>5 edge parity, c2 = (lane&31)*2 column pair. 16-edge predicated batches,
// 8 paired gathers in flight. XCD pinning: id%8 -> group, type = group>>2.

__global__ void spmm_kernel(const unsigned short* __restrict__ Ybase,
                            const int* __restrict__ rowptr, const unsigned int* __restrict__ edges,
                            unsigned short* __restrict__ act, float* __restrict__ outp,
                            int N, int E2, int relu) {
    int id = blockIdx.x;
    int g = id & 7;
    int t = g >> 2;
    int pbi = (id >> 3) * 4 + (g & 3);
    int wave = threadIdx.x >> 6;
    int lane = threadIdx.x & 63;
    int d = pbi * 4 + wave;
    if (d >= N) return;
    int h = lane >> 5;
    int c2 = (lane & 31) * 2;
    const unsigned short* Y = Ybase + (size_t)(2 * t) * N * HD;
    const unsigned int* ep = edges + (size_t)t * E2;
    int beg = rowptr[(size_t)t * (N + 1) + d];
    int end = rowptr[(size_t)t * (N + 1) + d + 1];
    float2 a[8];
    #pragma unroll
    for (int j = 0; j < 8; ++j) a[j] = make_float2(0.f, 0.f);
    if (beg < end) {
        int endm1 = end - 1;
        unsigned int m[8];
        #pragma unroll
        for (int j = 0; j < 8; ++j) {
            int idx = beg + 2 * j + h;
            m[j] = ep[idx < end ? idx : endm1];
        }
        for (int base = beg; ; ) {
            int nb = base + 16;
            bool more = nb < end;
            unsigned int n[8];
            if (more) {
                #pragma unroll
                for (int j = 0; j < 8; ++j) {
                    int idx = nb + 2 * j + h;
                    n[j] = ep[idx < end ? idx : endm1];
                }
            }
            #pragma unroll
            for (int j = 0; j < 8; ++j) {
                unsigned int q = m[j];
                unsigned int yv =
                    *reinterpret_cast<const unsigned int*>(Y + ((q & 0x1FFFFu) * HD + c2));
                float w = ((base + 2 * j + h) < end) ? __uint_as_float((q >> 17) << 16) : 0.f;
                a[j].x += w * bflo(yv);
                a[j].y += w * bfhi(yv);
            }
            if (!more) break;
            base = nb;
            #pragma unroll
            for (int j = 0; j < 8; ++j) m[j] = n[j];
        }
    }
    float2 s;
    s.x = ((a[0].x + a[1].x) + (a[2].x + a[3].x)) + ((a[4].x + a[5].x) + (a[6].x + a[7].x));
    s.y = ((a[0].y + a[1].y) + (a[2].y + a[3].y)) + ((a[4].y + a[5].y) + (a[6].y + a[7].y));
    s.x += __shfl_xor(s.x, 32, 64);
    s.y += __shfl_xor(s.y, 32, 64);
    if (relu) { s.x = fmaxf(s.x, 0.f); s.y = fmaxf(s.y, 0.f); }
    if (lane < 32) {
        if (act) {
            ushort2 ob; ob.x = f2bf(s.x); ob.y = f2bf(s.y);
            *reinterpret_cast<ushort2*>(&act[((size_t)t * N + d) * HD + c2]) = ob;
        }
        if (outp) *reinterpret_cast<float2*>(&outp[((size_t)t * N + d) * 192 + c2]) = s;
    }
}

// ---------------- orchestration ----------------

extern "C" void kernel_launch(void* const* d_in, const int* in_sizes, int n_in,
                              void* d_out, int out_size, void* d_ws, size_t ws_size,
                              hipStream_t stream) {
    const float* x0 = (const float*)d_in[0];
    const float* x1 = (const float*)d_in[1];
    const int* src = (const int*)d_in[2];
    const int* dst = (const int*)d_in[3];
    const float* ew = (const float*)d_in[4];
    const float* W1 = (const float*)d_in[5];
    const float* Wl = (const float*)d_in[6];
    float* out = (float*)d_out;

    int N = in_sizes[0] / FD;
    int E = in_sizes[2] / NREL;
    int E2 = 2 * E;                 // edges per super-relation
    int NBP = idiv_up(N, BUCKET);   // 782 for N=50000 (must be <= 1024 for bscan)

    char* ws = (char*)d_ws;
    size_t off = 0;
    auto alloc = [&](size_t bytes) -> void* {
        void* p = ws + off;
        off = (off + bytes + 255) & ~(size_t)255;
        return p;
    };
    int* bhist   = (int*)alloc((size_t)NSUP * NBP * 4);
    int* bptr    = (int*)alloc((size_t)NSUP * (NBP + 1) * 4);
    int* gcur    = (int*)alloc((size_t)NSUP * NBP * 4);
    int* rowptr  = (int*)alloc((size_t)NSUP * (N + 1) * 4);
    unsigned int* edges = (unsigned int*)alloc((size_t)NSUP * E2 * 4);
    unsigned short* y    = (unsigned short*)alloc((size_t)NREL * N * HD * 2);
    unsigned short* xb   = (unsigned short*)alloc((size_t)2 * N * FD * 2);
    unsigned short* actb = (unsigned short*)alloc((size_t)2 * N * HD * 2);
    unsigned short* W1f  = (unsigned short*)alloc((size_t)NREL * 4 * 4 * 64 * 8 * 2);
    unsigned short* Wlf  = (unsigned short*)alloc((size_t)16 * 2 * 4 * 64 * 8 * 2);
    int2* staged = (int2*)alloc((size_t)NSUP * E2 * 8);   // dead after bsort
    (void)ws_size;

    // input converts
    int nq = N * FD / 4;
    convx_kernel<<<2048, 256, 0, stream>>>(x0, x1, xb, nq);
    convw_kernel<<<idiv_up(NREL * 4 * 4 * 64, 256), 256, 0, stream>>>(W1, W1f, NREL, 4);
    convw_kernel<<<idiv_up(16 * 2 * 4 * 64, 256), 256, 0, stream>>>(Wl, Wlf, 16, 2);

    // bucket partition + per-bucket counting sort (recomputed every call)
    hipMemsetAsync(bhist, 0, (size_t)NSUP * NBP * 4, stream);
    dim3 egrid(idiv_up(E2, CHUNK), NSUP);
    bhist_kernel<<<egrid, 256, NBP * 4, stream>>>(dst, bhist, E2, NBP);
    bscan_kernel<<<NSUP, 1024, 0, stream>>>(bhist, bptr, gcur, NBP, E2);
    part_kernel<<<egrid, 256, 2 * NBP * 4, stream>>>(src, dst, ew, gcur, staged, E, E2, N, NBP);
    bsort_kernel<<<dim3(NBP, NSUP), 256, 0, stream>>>(staged, bptr, rowptr, edges, E2, N, NBP);

    dim3 ggrid(idiv_up(N, 128), NREL);
    int NB4 = idiv_up(N, 4);
    int sgx = idiv_up(NB4, 4) * 8;   // flat grid, id%8 -> (type, xcd-slot)

    // layer 1: h1 = relu(spmm(x @ W1)); store act(bf16) + out[:, :, 0:64]
    gemm_mfma_kernel<FD><<<ggrid, 256, 0, stream>>>(xb, W1f, y, N);
    spmm_kernel<<<sgx, 256, 0, stream>>>(y, rowptr, edges, actb, out + 0, N, E2, 1);

    // layers 2..5 with Wl[0..3]
    for (int l = 0; l < 4; ++l) {
        gemm_mfma_kernel<HD><<<ggrid, 256, 0, stream>>>(
            actb, Wlf + (size_t)l * 4 * 2 * 4 * 64 * 8, y, N);
        float* op = (l == 0) ? (out + 64) : (l == 3) ? (out + 128) : nullptr;
        unsigned short* ap = (l == 3) ? nullptr : actb;
        int relu = (l == 3) ? 0 : 1;
        spmm_kernel<<<sgx, 256, 0, stream>>>(y, rowptr, edges, ap, op, N, E2, relu);
    }
}

// Round 9
// 485.519 us; speedup vs baseline: 12.7683x; 1.0540x over previous
//
#include <hip/hip_runtime.h>
#include <cstddef>

#define NREL 4
#define NSUP 2         // super-relations (pairs of relations sharing a dst type)
#define HD 64
#define FD 128
#define BSHIFT 6
#define BUCKET 64      // nodes per bucket
#define CHUNK 2048     // edges per partition block (small => enough blocks for latency hiding)

static inline int idiv_up(int a, int b) { return (a + b - 1) / b; }

typedef __attribute__((ext_vector_type(8))) short bf16x8;
typedef __attribute__((ext_vector_type(4))) float f32x4;

__device__ __forceinline__ unsigned short f2bf(float f) {
    unsigned int u = __float_as_uint(f);
    unsigned int r = (u + 0x7FFFu + ((u >> 16) & 1u)) >> 16;   // RNE
    return (unsigned short)r;
}
__device__ __forceinline__ float bflo(unsigned int v) {
    return __uint_as_float(v << 16);
}
__device__ __forceinline__ float bfhi(unsigned int v) {
    return __uint_as_float(v & 0xFFFF0000u);
}

// ---------------- pass A: per-super-relation bucket histogram ----------------

__global__ void bhist_kernel(const int* __restrict__ dst, int* __restrict__ bhist,
                             int E2, int NBP) {
    int k = blockIdx.y;
    extern __shared__ int lh[];
    for (int i = threadIdx.x; i < NBP; i += blockDim.x) lh[i] = 0;
    __syncthreads();
    const int* dk = dst + (size_t)k * E2;
    for (int e = blockIdx.x * blockDim.x + threadIdx.x; e < E2; e += gridDim.x * blockDim.x)
        atomicAdd(&lh[dk[e] >> BSHIFT], 1);
    __syncthreads();
    int* bh = bhist + (size_t)k * NBP;
    for (int i = threadIdx.x; i < NBP; i += blockDim.x)
        if (lh[i]) atomicAdd(&bh[i], lh[i]);
}

// ---------------- pass B: exclusive scan of bucket counts (NBP <= 1024) ----------------

__global__ void bscan_kernel(const int* __restrict__ bhist, int* __restrict__ bptr,
                             int* __restrict__ gcur, int NBP, int E2) {
    int k = blockIdx.x;
    __shared__ int wsum[16];
    int tid = threadIdx.x, wid = tid >> 6, lane = tid & 63;
    int v = (tid < NBP) ? bhist[(size_t)k * NBP + tid] : 0;
    int x = v;
    #pragma unroll
    for (int off = 1; off < 64; off <<= 1) {
        int y = __shfl_up(x, off, 64);
        if (lane >= off) x += y;
    }
    if (lane == 63) wsum[wid] = x;
    __syncthreads();
    if (wid == 0) {
        int s = (lane < 16) ? wsum[lane] : 0;
        #pragma unroll
        for (int off = 1; off < 16; off <<= 1) {
            int y = __shfl_up(s, off, 64);
            if (lane >= off) s += y;
        }
        if (lane < 16) wsum[lane] = s;
    }
    __syncthreads();
    int excl = x - v + (wid ? wsum[wid - 1] : 0);
    if (tid < NBP) {
        bptr[(size_t)k * (NBP + 1) + tid] = excl;
        gcur[(size_t)k * NBP + tid] = excl;
    }
    if (tid == 0) bptr[(size_t)k * (NBP + 1) + NBP] = E2;
}

// ---------------- pass C: block-aggregated bucket partition ----------------
// staged[pos] = { row17 | (dst_local6 << 17), bits(w) }, grouped by dst bucket.
// row = src + N * (edge belongs to 2nd relation of the pair).

__global__ void part_kernel(const int* __restrict__ src, const int* __restrict__ dst,
                            const float* __restrict__ ew, int* __restrict__ gcur,
                            int2* __restrict__ staged, int E, int E2, int N, int NBP) {
    int k = blockIdx.y;
    extern __shared__ int sh[];
    int* lcnt = sh;          // NBP
    int* lbase = sh + NBP;   // NBP
    for (int i = threadIdx.x; i < NBP; i += blockDim.x) lcnt[i] = 0;
    __syncthreads();
    const int* sk = src + (size_t)k * E2;
    const int* dk = dst + (size_t)k * E2;
    const float* wk = ew + (size_t)k * E2;
    int base = blockIdx.x * CHUNK;
    int n = min(CHUNK, E2 - base);
    for (int i = threadIdx.x; i < n; i += blockDim.x)
        atomicAdd(&lcnt[dk[base + i] >> BSHIFT], 1);
    __syncthreads();
    for (int i = threadIdx.x; i < NBP; i += blockDim.x) {
        int c = lcnt[i];
        lbase[i] = c ? atomicAdd(&gcur[(size_t)k * NBP + i], c) : 0;
    }
    __syncthreads();
    for (int i = threadIdx.x; i < NBP; i += blockDim.x) lcnt[i] = 0;
    __syncthreads();
    int2* out = staged + (size_t)k * E2;
    for (int i = threadIdx.x; i < n; i += blockDim.x) {
        int gi = base + i;
        int d = dk[gi];
        int b = d >> BSHIFT;
        int row = sk[gi] + ((gi >= E) ? N : 0);
        int local = atomicAdd(&lcnt[b], 1);
        out[lbase[b] + local] =
            make_int2(row | ((d & (BUCKET - 1)) << 17), __float_as_int(wk[gi]));
    }
}

// ---------------- pass D: per-bucket LDS counting sort -> node-sorted 4B edges + rowptr --

__global__ void bsort_kernel(const int2* __restrict__ staged, const int* __restrict__ bptr,
                             int* __restrict__ rowptr, unsigned int* __restrict__ edges,
                             int E2, int N, int NBP) {
    int k = blockIdx.y;
    int b = blockIdx.x;
    __shared__ int hist[BUCKET];
    __shared__ int excl[BUCKET];
    __shared__ int cur[BUCKET];
    int tid = threadIdx.x;
    if (tid < BUCKET) hist[tid] = 0;
    __syncthreads();
    int beg = bptr[(size_t)k * (NBP + 1) + b];
    int end = bptr[(size_t)k * (NBP + 1) + b + 1];
    const int2* in = staged + (size_t)k * E2;
    for (int i = beg + tid; i < end; i += blockDim.x)
        atomicAdd(&hist[(in[i].x >> 17) & (BUCKET - 1)], 1);
    __syncthreads();
    if (tid < 64) {
        int v = hist[tid];
        int x = v;
        #pragma unroll
        for (int off = 1; off < 64; off <<= 1) {
            int y = __shfl_up(x, off, 64);
            if (tid >= off) x += y;
        }
        excl[tid] = x - v;
        cur[tid] = x - v;
    }
    __syncthreads();
    unsigned int* outp = edges + (size_t)k * E2;
    for (int i = beg + tid; i < end; i += blockDim.x) {
        int2 q = in[i];
        int dl = (q.x >> 17) & (BUCKET - 1);
        int pos = atomicAdd(&cur[dl], 1);
        unsigned int wb = (unsigned int)(f2bf(__int_as_float(q.y)) & 0x7FFF);
        outp[beg + pos] = ((unsigned int)q.x & 0x1FFFFu) | (wb << 17);
    }
    int node0 = b * BUCKET;
    if (tid < BUCKET && node0 + tid < N)
        rowptr[(size_t)k * (N + 1) + node0 + tid] = beg + excl[tid];
    if (b == 0 && tid == 0) rowptr[(size_t)k * (N + 1) + N] = E2;
}

// ---------------- converts: x -> bf16, W -> bf16 fragment-swizzled ----------------

__global__ void convx_kernel(const float* __restrict__ x0, const float* __restrict__ x1,
                             unsigned short* __restrict__ xb, int nq /* quads per array */) {
    for (int i = blockIdx.x * blockDim.x + threadIdx.x; i < 2 * nq;
         i += gridDim.x * blockDim.x) {
        const float4* xs = (i < nq) ? (const float4*)x0 : (const float4*)x1;
        int j = (i < nq) ? i : i - nq;
        float4 v = xs[j];
        ushort4 o;
        o.x = f2bf(v.x); o.y = f2bf(v.y); o.z = f2bf(v.z); o.w = f2bf(v.w);
        reinterpret_cast<ushort4*>(xb)[i] = o;
    }
}

// Wf[mat][kk][n][lane][i] = W[mat][kk*32 + (lane>>4)*8 + i][n*16 + (lane&15)]
__global__ void convw_kernel(const float* __restrict__ W, unsigned short* __restrict__ Wf,
                             int mats, int KK) {
    int tid = blockIdx.x * blockDim.x + threadIdx.x;
    int total = mats * KK * 4 * 64;
    if (tid >= total) return;
    int l = tid & 63;
    int n = (tid >> 6) & 3;
    int rest = tid >> 8;
    int kk = rest % KK;
    int mat = rest / KK;
    int h = l >> 4, c = l & 15;
    int K = KK * 32;
    const float* Wm = W + (size_t)mat * K * 64;
    unsigned short* o = Wf + (size_t)tid * 8;
    #pragma unroll
    for (int i = 0; i < 8; ++i)
        o[i] = f2bf(Wm[(size_t)(kk * 32 + h * 8 + i) * 64 + n * 16 + c]);
}

// ---------------- MFMA GEMM: Y[rel] = X_{rel%2} @ W_rel, bf16 in/out, f32 acc ----------

template <int K>
__global__ void gemm_mfma_kernel(const unsigned short* __restrict__ Xb,
                                 const unsigned short* __restrict__ Wf,
                                 unsigned short* __restrict__ Ybase, int N) {
    constexpr int KK = K / 32;
    int rel = blockIdx.y;
    const unsigned short* X = Xb + (size_t)(rel & 1) * N * K;
    const bf16x8* Wv = reinterpret_cast<const bf16x8*>(Wf + (size_t)rel * KK * 4 * 64 * 8);
    unsigned short* Y = Ybase + (size_t)rel * N * HD;
    int tid = threadIdx.x;
    int w = tid >> 6, l = tid & 63;
    int lr = l & 15, lh = l >> 4;
    int row0 = blockIdx.x * 128 + w * 32;
    f32x4 acc00 = {0.f,0.f,0.f,0.f}, acc01 = {0.f,0.f,0.f,0.f};
    f32x4 acc02 = {0.f,0.f,0.f,0.f}, acc03 = {0.f,0.f,0.f,0.f};
    f32x4 acc10 = {0.f,0.f,0.f,0.f}, acc11 = {0.f,0.f,0.f,0.f};
    f32x4 acc12 = {0.f,0.f,0.f,0.f}, acc13 = {0.f,0.f,0.f,0.f};
    int r0 = min(row0 + lr, N - 1);
    int r1 = min(row0 + 16 + lr, N - 1);
    const unsigned short* xp0 = X + (size_t)r0 * K + lh * 8;
    const unsigned short* xp1 = X + (size_t)r1 * K + lh * 8;
    #pragma unroll
    for (int kk = 0; kk < KK; ++kk) {
        bf16x8 a0 = *reinterpret_cast<const bf16x8*>(xp0 + kk * 32);
        bf16x8 a1 = *reinterpret_cast<const bf16x8*>(xp1 + kk * 32);
        bf16x8 b0 = Wv[(kk * 4 + 0) * 64 + l];
        bf16x8 b1 = Wv[(kk * 4 + 1) * 64 + l];
        bf16x8 b2 = Wv[(kk * 4 + 2) * 64 + l];
        bf16x8 b3 = Wv[(kk * 4 + 3) * 64 + l];
        acc00 = __builtin_amdgcn_mfma_f32_16x16x32_bf16(a0, b0, acc00, 0, 0, 0);
        acc01 = __builtin_amdgcn_mfma_f32_16x16x32_bf16(a0, b1, acc01, 0, 0, 0);
        acc02 = __builtin_amdgcn_mfma_f32_16x16x32_bf16(a0, b2, acc02, 0, 0, 0);
        acc03 = __builtin_amdgcn_mfma_f32_16x16x32_bf16(a0, b3, acc03, 0, 0, 0);
        acc10 = __builtin_amdgcn_mfma_f32_16x16x32_bf16(a1, b0, acc10, 0, 0, 0);
        acc11 = __builtin_amdgcn_mfma_f32_16x16x32_bf16(a1, b1, acc11, 0, 0, 0);
        acc12 = __builtin_amdgcn_mfma_f32_16x16x32_bf16(a1, b2, acc12, 0, 0, 0);
        acc13 = __builtin_amdgcn_mfma_f32_16x16x32_bf16(a1, b3, acc13, 0, 0, 0);
    }
    // C/D layout: col = lane&15, row(in tile) = (lane>>4)*4 + reg  [HW-verified]
    #pragma unroll
    for (int reg = 0; reg < 4; ++reg) {
        int rowa = row0 + lh * 4 + reg;
        if (rowa < N) {
            unsigned short* yp = Y + (size_t)rowa * HD + lr;
            yp[0]  = f2bf(acc00[reg]);
            yp[16] = f2bf(acc01[reg]);
            yp[32] = f2bf(acc02[reg]);
            yp[48] = f2bf(acc03[reg]);
        }
        int rowb = row0 + 16 + lh * 4 + reg;
        if (rowb < N) {
            unsigned short* yp = Y + (size_t)rowb * HD + lr;
            yp[0]  = f2bf(acc10[reg]);
            yp[16] = f2bf(acc11[reg]);
            yp[32] = f2bf(acc12[reg]);
            yp[48] = f2bf(acc13[reg]);
        }
    }
}

// ---------------- SpMM gather: one wave per dst node, combined relation pair ----------
// edge rec: row17 | wbf15<<17 (row < 2N indexes the contiguous y pair for this type).
// h = lane>>4 edge slot (4 edges per gather instr), c4 = (lane&15)*4 column quad
// (uint2 = 4 bf16 = 8 B/lane; 16 lanes cover a 128 B row). 16-edge predicated
// batches; 4 paired gathers (16 edges) in flight. XCD pinning: id%8 -> group.

__global__ void spmm_kernel(const unsigned short* __restrict__ Ybase,
                            const int* __restrict__ rowptr, const unsigned int* __restrict__ edges,
                            unsigned short* __restrict__ act, float* __restrict__ outp,
                            int N, int E2, int relu) {
    int id = blockIdx.x;
    int g = id & 7;
    int t = g >> 2;
    int pbi = (id >> 3) * 4 + (g & 3);
    int wave = threadIdx.x >> 6;
    int lane = threadIdx.x & 63;
    int d = pbi * 4 + wave;
    if (d >= N) return;
    int h = lane >> 4;          // edge slot 0..3
    int c4 = (lane & 15) * 4;   // column quad
    const unsigned short* Y = Ybase + (size_t)(2 * t) * N * HD;
    const unsigned int* ep = edges + (size_t)t * E2;
    int beg = rowptr[(size_t)t * (N + 1) + d];
    int end = rowptr[(size_t)t * (N + 1) + d + 1];
    float4 a0 = {0.f,0.f,0.f,0.f}, a1 = {0.f,0.f,0.f,0.f};
    float4 a2 = {0.f,0.f,0.f,0.f}, a3 = {0.f,0.f,0.f,0.f};
    if (beg < end) {
        int endm1 = end - 1;
        unsigned int m0, m1, m2, m3;
        {
            int i0 = beg + 0 + h, i1 = beg + 4 + h, i2 = beg + 8 + h, i3 = beg + 12 + h;
            m0 = ep[i0 < end ? i0 : endm1];
            m1 = ep[i1 < end ? i1 : endm1];
            m2 = ep[i2 < end ? i2 : endm1];
            m3 = ep[i3 < end ? i3 : endm1];
        }
        for (int base = beg; ; ) {
            int nb = base + 16;
            bool more = nb < end;
            unsigned int n0, n1, n2, n3;
            if (more) {
                int i0 = nb + 0 + h, i1 = nb + 4 + h, i2 = nb + 8 + h, i3 = nb + 12 + h;
                n0 = ep[i0 < end ? i0 : endm1];
                n1 = ep[i1 < end ? i1 : endm1];
                n2 = ep[i2 < end ? i2 : endm1];
                n3 = ep[i3 < end ? i3 : endm1];
            }
            uint2 y0 = *reinterpret_cast<const uint2*>(Y + ((m0 & 0x1FFFFu) * HD + c4));
            uint2 y1 = *reinterpret_cast<const uint2*>(Y + ((m1 & 0x1FFFFu) * HD + c4));
            uint2 y2 = *reinterpret_cast<const uint2*>(Y + ((m2 & 0x1FFFFu) * HD + c4));
            uint2 y3 = *reinterpret_cast<const uint2*>(Y + ((m3 & 0x1FFFFu) * HD + c4));
            float w0 = ((base + 0 + h) < end) ? __uint_as_float((m0 >> 17) << 16) : 0.f;
            float w1 = ((base + 4 + h) < end) ? __uint_as_float((m1 >> 17) << 16) : 0.f;
            float w2 = ((base + 8 + h) < end) ? __uint_as_float((m2 >> 17) << 16) : 0.f;
            float w3 = ((base + 12 + h) < end) ? __uint_as_float((m3 >> 17) << 16) : 0.f;
            a0.x += w0 * bflo(y0.x); a0.y += w0 * bfhi(y0.x);
            a0.z += w0 * bflo(y0.y); a0.w += w0 * bfhi(y0.y);
            a1.x += w1 * bflo(y1.x); a1.y += w1 * bfhi(y1.x);
            a1.z += w1 * bflo(y1.y); a1.w += w1 * bfhi(y1.y);
            a2.x += w2 * bflo(y2.x); a2.y += w2 * bfhi(y2.x);
            a2.z += w2 * bflo(y2.y); a2.w += w2 * bfhi(y2.y);
            a3.x += w3 * bflo(y3.x); a3.y += w3 * bfhi(y3.x);
            a3.z += w3 * bflo(y3.y); a3.w += w3 * bfhi(y3.y);
            if (!more) break;
            base = nb;
            m0 = n0; m1 = n1; m2 = n2; m3 = n3;
        }
    }
    float4 s;
    s.x = (a0.x + a1.x) + (a2.x + a3.x);
    s.y = (a0.y + a1.y) + (a2.y + a3.y);
    s.z = (a0.z + a1.z) + (a2.z + a3.z);
    s.w = (a0.w + a1.w) + (a2.w + a3.w);
    s.x += __shfl_xor(s.x, 16, 64);  s.x += __shfl_xor(s.x, 32, 64);
    s.y += __shfl_xor(s.y, 16, 64);  s.y += __shfl_xor(s.y, 32, 64);
    s.z += __shfl_xor(s.z, 16, 64);  s.z += __shfl_xor(s.z, 32, 64);
    s.w += __shfl_xor(s.w, 16, 64);  s.w += __shfl_xor(s.w, 32, 64);
    if (relu) {
        s.x = fmaxf(s.x, 0.f); s.y = fmaxf(s.y, 0.f);
        s.z = fmaxf(s.z, 0.f); s.w = fmaxf(s.w, 0.f);
    }
    if (lane < 16) {
        if (act) {
            ushort4 ob;
            ob.x = f2bf(s.x); ob.y = f2bf(s.y); ob.z = f2bf(s.z); ob.w = f2bf(s.w);
            *reinterpret_cast<ushort4*>(&act[((size_t)t * N + d) * HD + c4]) = ob;
        }
        if (outp) *reinterpret_cast<float4*>(&outp[((size_t)t * N + d) * 192 + c4]) = s;
    }
}

// ---------------- orchestration ----------------

extern "C" void kernel_launch(void* const* d_in, const int* in_sizes, int n_in,
                              void* d_out, int out_size, void* d_ws, size_t ws_size,
                              hipStream_t stream) {
    const float* x0 = (const float*)d_in[0];
    const float* x1 = (const float*)d_in[1];
    const int* src = (const int*)d_in[2];
    const int* dst = (const int*)d_in[3];
    const float* ew = (const float*)d_in[4];
    const float* W1 = (const float*)d_in[5];
    const float* Wl = (const float*)d_in[6];
    float* out = (float*)d_out;

    int N = in_sizes[0] / FD;
    int E = in_sizes[2] / NREL;
    int E2 = 2 * E;                 // edges per super-relation
    int NBP = idiv_up(N, BUCKET);   // 782 for N=50000 (must be <= 1024 for bscan)

    char* ws = (char*)d_ws;
    size_t off = 0;
    auto alloc = [&](size_t bytes) -> void* {
        void* p = ws + off;
        off = (off + bytes + 255) & ~(size_t)255;
        return p;
    };
    int* bhist   = (int*)alloc((size_t)NSUP * NBP * 4);
    int* bptr    = (int*)alloc((size_t)NSUP * (NBP + 1) * 4);
    int* gcur    = (int*)alloc((size_t)NSUP * NBP * 4);
    int* rowptr  = (int*)alloc((size_t)NSUP * (N + 1) * 4);
    unsigned int* edges = (unsigned int*)alloc((size_t)NSUP * E2 * 4);
    unsigned short* y    = (unsigned short*)alloc((size_t)NREL * N * HD * 2);
    unsigned short* xb   = (unsigned short*)alloc((size_t)2 * N * FD * 2);
    unsigned short* actb = (unsigned short*)alloc((size_t)2 * N * HD * 2);
    unsigned short* W1f  = (unsigned short*)alloc((size_t)NREL * 4 * 4 * 64 * 8 * 2);
    unsigned short* Wlf  = (unsigned short*)alloc((size_t)16 * 2 * 4 * 64 * 8 * 2);
    int2* staged = (int2*)alloc((size_t)NSUP * E2 * 8);   // dead after bsort
    (void)ws_size;

    // input converts
    int nq = N * FD / 4;
    convx_kernel<<<2048, 256, 0, stream>>>(x0, x1, xb, nq);
    convw_kernel<<<idiv_up(NREL * 4 * 4 * 64, 256), 256, 0, stream>>>(W1, W1f, NREL, 4);
    convw_kernel<<<idiv_up(16 * 2 * 4 * 64, 256), 256, 0, stream>>>(Wl, Wlf, 16, 2);

    // bucket partition + per-bucket counting sort (recomputed every call)
    hipMemsetAsync(bhist, 0, (size_t)NSUP * NBP * 4, stream);
    bhist_kernel<<<dim3(384, NSUP), 256, NBP * 4, stream>>>(dst, bhist, E2, NBP);
    bscan_kernel<<<NSUP, 1024, 0, stream>>>(bhist, bptr, gcur, NBP, E2);
    part_kernel<<<dim3(idiv_up(E2, CHUNK), NSUP), 256, 2 * NBP * 4, stream>>>(
        src, dst, ew, gcur, staged, E, E2, N, NBP);
    bsort_kernel<<<dim3(NBP, NSUP), 256, 0, stream>>>(staged, bptr, rowptr, edges, E2, N, NBP);

    dim3 ggrid(idiv_up(N, 128), NREL);
    int NB4 = idiv_up(N, 4);
    int sgx = idiv_up(NB4, 4) * 8;   // flat grid, id%8 -> (type, xcd-slot)

    // layer 1: h1 = relu(spmm(x @ W1)); store act(bf16) + out[:, :, 0:64]
    gemm_mfma_kernel<FD><<<ggrid, 256, 0, stream>>>(xb, W1f, y, N);
    spmm_kernel<<<sgx, 256, 0, stream>>>(y, rowptr, edges, actb, out + 0, N, E2, 1);

    // layers 2..5 with Wl[0..3]
    for (int l = 0; l < 4; ++l) {
        gemm_mfma_kernel<HD><<<ggrid, 256, 0, stream>>>(
            actb, Wlf + (size_t)l * 4 * 2 * 4 * 64 * 8, y, N);
        float* op = (l == 0) ? (out + 64) : (l == 3) ? (out + 128) : nullptr;
        unsigned short* ap = (l == 3) ? nullptr : actb;
        int relu = (l == 3) ? 0 : 1;
        spmm_kernel<<<sgx, 256, 0, stream>>>(y, rowptr, edges, ap, op, N, E2, relu);
    }
}

// Round 10
// 432.565 us; speedup vs baseline: 14.3314x; 1.1224x over previous
//
#include <hip/hip_runtime.h>
#include <cstddef>

#define NREL 4
#define NSUP 2         // super-relations (pairs of relations sharing a dst type)
#define HD 64
#define FD 128
#define BSHIFT 8
#define BUCKET 256     // nodes per bucket
#define CHUNK 16384    // edges per partition block

static inline int idiv_up(int a, int b) { return (a + b - 1) / b; }

typedef __attribute__((ext_vector_type(8))) short bf16x8;
typedef __attribute__((ext_vector_type(4))) float f32x4;

__device__ __forceinline__ unsigned short f2bf(float f) {
    unsigned int u = __float_as_uint(f);
    unsigned int r = (u + 0x7FFFu + ((u >> 16) & 1u)) >> 16;   // RNE
    return (unsigned short)r;
}
__device__ __forceinline__ float bflo(unsigned int v) {
    return __uint_as_float(v << 16);
}
__device__ __forceinline__ float bfhi(unsigned int v) {
    return __uint_as_float(v & 0xFFFF0000u);
}

// ---------------- pass A: per-super-relation bucket histogram ----------------

__global__ void bhist_kernel(const int* __restrict__ dst, int* __restrict__ bhist,
                             int E2, int NBP) {
    int k = blockIdx.y;
    extern __shared__ int lh[];
    for (int i = threadIdx.x; i < NBP; i += blockDim.x) lh[i] = 0;
    __syncthreads();
    const int* dk = dst + (size_t)k * E2;
    for (int e = blockIdx.x * blockDim.x + threadIdx.x; e < E2; e += gridDim.x * blockDim.x)
        atomicAdd(&lh[dk[e] >> BSHIFT], 1);
    __syncthreads();
    int* bh = bhist + (size_t)k * NBP;
    for (int i = threadIdx.x; i < NBP; i += blockDim.x)
        if (lh[i]) atomicAdd(&bh[i], lh[i]);
}

// ---------------- pass B: exclusive scan of bucket counts (NBP <= 1024) ----------------

__global__ void bscan_kernel(const int* __restrict__ bhist, int* __restrict__ bptr,
                             int* __restrict__ gcur, int NBP, int E2) {
    int k = blockIdx.x;
    __shared__ int wsum[16];
    int tid = threadIdx.x, wid = tid >> 6, lane = tid & 63;
    int v = (tid < NBP) ? bhist[(size_t)k * NBP + tid] : 0;
    int x = v;
    #pragma unroll
    for (int off = 1; off < 64; off <<= 1) {
        int y = __shfl_up(x, off, 64);
        if (lane >= off) x += y;
    }
    if (lane == 63) wsum[wid] = x;
    __syncthreads();
    if (wid == 0) {
        int s = (lane < 16) ? wsum[lane] : 0;
        #pragma unroll
        for (int off = 1; off < 16; off <<= 1) {
            int y = __shfl_up(s, off, 64);
            if (lane >= off) s += y;
        }
        if (lane < 16) wsum[lane] = s;
    }
    __syncthreads();
    int excl = x - v + (wid ? wsum[wid - 1] : 0);
    if (tid < NBP) {
        bptr[(size_t)k * (NBP + 1) + tid] = excl;
        gcur[(size_t)k * NBP + tid] = excl;
    }
    if (tid == 0) bptr[(size_t)k * (NBP + 1) + NBP] = E2;
}

// ---------------- pass C: block-aggregated bucket partition (1024 threads) ----------
// staged[pos] = { row17 | (dst_local8 << 17), bits(w) }, grouped by dst bucket.
// row = src + N * (edge belongs to 2nd relation of the pair).

__global__ void part_kernel(const int* __restrict__ src, const int* __restrict__ dst,
                            const float* __restrict__ ew, int* __restrict__ gcur,
                            int2* __restrict__ staged, int E, int E2, int N, int NBP) {
    int k = blockIdx.y;
    extern __shared__ int sh[];
    int* lcnt = sh;          // NBP
    int* lbase = sh + NBP;   // NBP
    for (int i = threadIdx.x; i < NBP; i += blockDim.x) lcnt[i] = 0;
    __syncthreads();
    const int* sk = src + (size_t)k * E2;
    const int* dk = dst + (size_t)k * E2;
    const float* wk = ew + (size_t)k * E2;
    int base = blockIdx.x * CHUNK;
    int n = min(CHUNK, E2 - base);
    for (int i = threadIdx.x; i < n; i += blockDim.x)
        atomicAdd(&lcnt[dk[base + i] >> BSHIFT], 1);
    __syncthreads();
    for (int i = threadIdx.x; i < NBP; i += blockDim.x) {
        int c = lcnt[i];
        lbase[i] = c ? atomicAdd(&gcur[(size_t)k * NBP + i], c) : 0;
    }
    __syncthreads();
    for (int i = threadIdx.x; i < NBP; i += blockDim.x) lcnt[i] = 0;
    __syncthreads();
    int2* out = staged + (size_t)k * E2;
    for (int i = threadIdx.x; i < n; i += blockDim.x) {
        int gi = base + i;
        int d = dk[gi];
        int b = d >> BSHIFT;
        int row = sk[gi] + ((gi >= E) ? N : 0);
        int local = atomicAdd(&lcnt[b], 1);
        out[lbase[b] + local] =
            make_int2(row | ((d & (BUCKET - 1)) << 17), __float_as_int(wk[gi]));
    }
}

// ---------------- pass D: per-bucket LDS counting sort (1024 threads) ----------------
// -> node-sorted 4B edge recs + rowptr

__global__ void bsort_kernel(const int2* __restrict__ staged, const int* __restrict__ bptr,
                             int* __restrict__ rowptr, unsigned int* __restrict__ edges,
                             int E2, int N, int NBP) {
    int k = blockIdx.y;
    int b = blockIdx.x;
    __shared__ int hist[BUCKET];
    __shared__ int excl[BUCKET];
    __shared__ int cur[BUCKET];
    __shared__ int wsum2[4];
    int tid = threadIdx.x;
    int wid = tid >> 6, lane = tid & 63;
    if (tid < BUCKET) hist[tid] = 0;
    __syncthreads();
    int beg = bptr[(size_t)k * (NBP + 1) + b];
    int end = bptr[(size_t)k * (NBP + 1) + b + 1];
    const int2* in = staged + (size_t)k * E2;
    for (int i = beg + tid; i < end; i += blockDim.x)
        atomicAdd(&hist[(in[i].x >> 17) & (BUCKET - 1)], 1);
    __syncthreads();
    int v = 0, x = 0;
    if (tid < BUCKET) {   // 4 full waves scan 64 each
        v = hist[tid];
        x = v;
        #pragma unroll
        for (int off = 1; off < 64; off <<= 1) {
            int y = __shfl_up(x, off, 64);
            if (lane >= off) x += y;
        }
        if (lane == 63) wsum2[wid] = x;
    }
    __syncthreads();
    if (tid == 0) {
        int s = 0;
        #pragma unroll
        for (int j = 0; j < 4; ++j) { int t = wsum2[j]; wsum2[j] = s; s += t; }
    }
    __syncthreads();
    if (tid < BUCKET) {
        int e = x - v + wsum2[wid];
        excl[tid] = e;
        cur[tid] = e;
    }
    __syncthreads();
    unsigned int* outp = edges + (size_t)k * E2;
    for (int i = beg + tid; i < end; i += blockDim.x) {
        int2 q = in[i];
        int dl = (q.x >> 17) & (BUCKET - 1);
        int pos = atomicAdd(&cur[dl], 1);
        unsigned int wb = (unsigned int)(f2bf(__int_as_float(q.y)) & 0x7FFF);
        outp[beg + pos] = ((unsigned int)q.x & 0x1FFFFu) | (wb << 17);
    }
    int node0 = b * BUCKET;
    if (tid < BUCKET && node0 + tid < N)
        rowptr[(size_t)k * (N + 1) + node0 + tid] = beg + excl[tid];
    if (b == 0 && tid == 0) rowptr[(size_t)k * (N + 1) + N] = E2;
}

// ---------------- converts: x -> bf16, W -> bf16 fragment-swizzled ----------------

__global__ void convx_kernel(const float* __restrict__ x0, const float* __restrict__ x1,
                             unsigned short* __restrict__ xb, int nq /* quads per array */) {
    for (int i = blockIdx.x * blockDim.x + threadIdx.x; i < 2 * nq;
         i += gridDim.x * blockDim.x) {
        const float4* xs = (i < nq) ? (const float4*)x0 : (const float4*)x1;
        int j = (i < nq) ? i : i - nq;
        float4 v = xs[j];
        ushort4 o;
        o.x = f2bf(v.x); o.y = f2bf(v.y); o.z = f2bf(v.z); o.w = f2bf(v.w);
        reinterpret_cast<ushort4*>(xb)[i] = o;
    }
}

// Wf[mat][kk][n][lane][i] = W[mat][kk*32 + (lane>>4)*8 + i][n*16 + (lane&15)]
__global__ void convw_kernel(const float* __restrict__ W, unsigned short* __restrict__ Wf,
                             int mats, int KK) {
    int tid = blockIdx.x * blockDim.x + threadIdx.x;
    int total = mats * KK * 4 * 64;
    if (tid >= total) return;
    int l = tid & 63;
    int n = (tid >> 6) & 3;
    int rest = tid >> 8;
    int kk = rest % KK;
    int mat = rest / KK;
    int h = l >> 4, c = l & 15;
    int K = KK * 32;
    const float* Wm = W + (size_t)mat * K * 64;
    unsigned short* o = Wf + (size_t)tid * 8;
    #pragma unroll
    for (int i = 0; i < 8; ++i)
        o[i] = f2bf(Wm[(size_t)(kk * 32 + h * 8 + i) * 64 + n * 16 + c]);
}

// ---------------- MFMA GEMM: Y[rel] = X_{rel%2} @ W_rel, bf16 in/out, f32 acc ----------

template <int K>
__global__ void gemm_mfma_kernel(const unsigned short* __restrict__ Xb,
                                 const unsigned short* __restrict__ Wf,
                                 unsigned short* __restrict__ Ybase, int N) {
    constexpr int KK = K / 32;
    int rel = blockIdx.y;
    const unsigned short* X = Xb + (size_t)(rel & 1) * N * K;
    const bf16x8* Wv = reinterpret_cast<const bf16x8*>(Wf + (size_t)rel * KK * 4 * 64 * 8);
    unsigned short* Y = Ybase + (size_t)rel * N * HD;
    int tid = threadIdx.x;
    int w = tid >> 6, l = tid & 63;
    int lr = l & 15, lh = l >> 4;
    int row0 = blockIdx.x * 128 + w * 32;
    f32x4 acc00 = {0.f,0.f,0.f,0.f}, acc01 = {0.f,0.f,0.f,0.f};
    f32x4 acc02 = {0.f,0.f,0.f,0.f}, acc03 = {0.f,0.f,0.f,0.f};
    f32x4 acc10 = {0.f,0.f,0.f,0.f}, acc11 = {0.f,0.f,0.f,0.f};
    f32x4 acc12 = {0.f,0.f,0.f,0.f}, acc13 = {0.f,0.f,0.f,0.f};
    int r0 = min(row0 + lr, N - 1);
    int r1 = min(row0 + 16 + lr, N - 1);
    const unsigned short* xp0 = X + (size_t)r0 * K + lh * 8;
    const unsigned short* xp1 = X + (size_t)r1 * K + lh * 8;
    #pragma unroll
    for (int kk = 0; kk < KK; ++kk) {
        bf16x8 a0 = *reinterpret_cast<const bf16x8*>(xp0 + kk * 32);
        bf16x8 a1 = *reinterpret_cast<const bf16x8*>(xp1 + kk * 32);
        bf16x8 b0 = Wv[(kk * 4 + 0) * 64 + l];
        bf16x8 b1 = Wv[(kk * 4 + 1) * 64 + l];
        bf16x8 b2 = Wv[(kk * 4 + 2) * 64 + l];
        bf16x8 b3 = Wv[(kk * 4 + 3) * 64 + l];
        acc00 = __builtin_amdgcn_mfma_f32_16x16x32_bf16(a0, b0, acc00, 0, 0, 0);
        acc01 = __builtin_amdgcn_mfma_f32_16x16x32_bf16(a0, b1, acc01, 0, 0, 0);
        acc02 = __builtin_amdgcn_mfma_f32_16x16x32_bf16(a0, b2, acc02, 0, 0, 0);
        acc03 = __builtin_amdgcn_mfma_f32_16x16x32_bf16(a0, b3, acc03, 0, 0, 0);
        acc10 = __builtin_amdgcn_mfma_f32_16x16x32_bf16(a1, b0, acc10, 0, 0, 0);
        acc11 = __builtin_amdgcn_mfma_f32_16x16x32_bf16(a1, b1, acc11, 0, 0, 0);
        acc12 = __builtin_amdgcn_mfma_f32_16x16x32_bf16(a1, b2, acc12, 0, 0, 0);
        acc13 = __builtin_amdgcn_mfma_f32_16x16x32_bf16(a1, b3, acc13, 0, 0, 0);
    }
    // C/D layout: col = lane&15, row(in tile) = (lane>>4)*4 + reg  [HW-verified]
    #pragma unroll
    for (int reg = 0; reg < 4; ++reg) {
        int rowa = row0 + lh * 4 + reg;
        if (rowa < N) {
            unsigned short* yp = Y + (size_t)rowa * HD + lr;
            yp[0]  = f2bf(acc00[reg]);
            yp[16] = f2bf(acc01[reg]);
            yp[32] = f2bf(acc02[reg]);
            yp[48] = f2bf(acc03[reg]);
        }
        int rowb = row0 + 16 + lh * 4 + reg;
        if (rowb < N) {
            unsigned short* yp = Y + (size_t)rowb * HD + lr;
            yp[0]  = f2bf(acc10[reg]);
            yp[16] = f2bf(acc11[reg]);
            yp[32] = f2bf(acc12[reg]);
            yp[48] = f2bf(acc13[reg]);
        }
    }
}

// ---------------- SpMM gather: one wave per dst node, combined relation pair ----------
// edge rec: row17 | wbf15<<17 (row < 2N indexes the contiguous y pair for this type).
// h = lane>>4 edge slot (4 edges per gather instr), c4 = (lane&15)*4 column quad
// (uint2 = 4 bf16 = 8 B/lane; 16 lanes cover a 128 B row). 16-edge predicated
// batches; 4 paired gathers (16 edges) in flight. XCD pinning: id%8 -> group.

__global__ void spmm_kernel(const unsigned short* __restrict__ Ybase,
                            const int* __restrict__ rowptr, const unsigned int* __restrict__ edges,
                            unsigned short* __restrict__ act, float* __restrict__ outp,
                            int N, int E2, int relu) {
    int id = blockIdx.x;
    int g = id & 7;
    int t = g >> 2;
    int pbi = (id >> 3) * 4 + (g & 3);
    int wave = threadIdx.x >> 6;
    int lane = threadIdx.x & 63;
    int d = pbi * 4 + wave;
    if (d >= N) return;
    int h = lane >> 4;          // edge slot 0..3
    int c4 = (lane & 15) * 4;   // column quad
    const unsigned short* Y = Ybase + (size_t)(2 * t) * N * HD;
    const unsigned int* ep = edges + (size_t)t * E2;
    int beg = rowptr[(size_t)t * (N + 1) + d];
    int end = rowptr[(size_t)t * (N + 1) + d + 1];
    float4 a0 = {0.f,0.f,0.f,0.f}, a1 = {0.f,0.f,0.f,0.f};
    float4 a2 = {0.f,0.f,0.f,0.f}, a3 = {0.f,0.f,0.f,0.f};
    if (beg < end) {
        int endm1 = end - 1;
        unsigned int m0, m1, m2, m3;
        {
            int i0 = beg + 0 + h, i1 = beg + 4 + h, i2 = beg + 8 + h, i3 = beg + 12 + h;
            m0 = ep[i0 < end ? i0 : endm1];
            m1 = ep[i1 < end ? i1 : endm1];
            m2 = ep[i2 < end ? i2 : endm1];
            m3 = ep[i3 < end ? i3 : endm1];
        }
        for (int base = beg; ; ) {
            int nb = base + 16;
            bool more = nb < end;
            unsigned int n0, n1, n2, n3;
            if (more) {
                int i0 = nb + 0 + h, i1 = nb + 4 + h, i2 = nb + 8 + h, i3 = nb + 12 + h;
                n0 = ep[i0 < end ? i0 : endm1];
                n1 = ep[i1 < end ? i1 : endm1];
                n2 = ep[i2 < end ? i2 : endm1];
                n3 = ep[i3 < end ? i3 : endm1];
            }
            uint2 y0 = *reinterpret_cast<const uint2*>(Y + ((m0 & 0x1FFFFu) * HD + c4));
            uint2 y1 = *reinterpret_cast<const uint2*>(Y + ((m1 & 0x1FFFFu) * HD + c4));
            uint2 y2 = *reinterpret_cast<const uint2*>(Y + ((m2 & 0x1FFFFu) * HD + c4));
            uint2 y3 = *reinterpret_cast<const uint2*>(Y + ((m3 & 0x1FFFFu) * HD + c4));
            float w0 = ((base + 0 + h) < end) ? __uint_as_float((m0 >> 17) << 16) : 0.f;
            float w1 = ((base + 4 + h) < end) ? __uint_as_float((m1 >> 17) << 16) : 0.f;
            float w2 = ((base + 8 + h) < end) ? __uint_as_float((m2 >> 17) << 16) : 0.f;
            float w3 = ((base + 12 + h) < end) ? __uint_as_float((m3 >> 17) << 16) : 0.f;
            a0.x += w0 * bflo(y0.x); a0.y += w0 * bfhi(y0.x);
            a0.z += w0 * bflo(y0.y); a0.w += w0 * bfhi(y0.y);
            a1.x += w1 * bflo(y1.x); a1.y += w1 * bfhi(y1.x);
            a1.z += w1 * bflo(y1.y); a1.w += w1 * bfhi(y1.y);
            a2.x += w2 * bflo(y2.x); a2.y += w2 * bfhi(y2.x);
            a2.z += w2 * bflo(y2.y); a2.w += w2 * bfhi(y2.y);
            a3.x += w3 * bflo(y3.x); a3.y += w3 * bfhi(y3.x);
            a3.z += w3 * bflo(y3.y); a3.w += w3 * bfhi(y3.y);
            if (!more) break;
            base = nb;
            m0 = n0; m1 = n1; m2 = n2; m3 = n3;
        }
    }
    float4 s;
    s.x = (a0.x + a1.x) + (a2.x + a3.x);
    s.y = (a0.y + a1.y) + (a2.y + a3.y);
    s.z = (a0.z + a1.z) + (a2.z + a3.z);
    s.w = (a0.w + a1.w) + (a2.w + a3.w);
    s.x += __shfl_xor(s.x, 16, 64);  s.x += __shfl_xor(s.x, 32, 64);
    s.y += __shfl_xor(s.y, 16, 64);  s.y += __shfl_xor(s.y, 32, 64);
    s.z += __shfl_xor(s.z, 16, 64);  s.z += __shfl_xor(s.z, 32, 64);
    s.w += __shfl_xor(s.w, 16, 64);  s.w += __shfl_xor(s.w, 32, 64);
    if (relu) {
        s.x = fmaxf(s.x, 0.f); s.y = fmaxf(s.y, 0.f);
        s.z = fmaxf(s.z, 0.f); s.w = fmaxf(s.w, 0.f);
    }
    if (lane < 16) {
        if (act) {
            ushort4 ob;
            ob.x = f2bf(s.x); ob.y = f2bf(s.y); ob.z = f2bf(s.z); ob.w = f2bf(s.w);
            *reinterpret_cast<ushort4*>(&act[((size_t)t * N + d) * HD + c4]) = ob;
        }
        if (outp) *reinterpret_cast<float4*>(&outp[((size_t)t * N + d) * 192 + c4]) = s;
    }
}

// ---------------- orchestration ----------------

extern "C" void kernel_launch(void* const* d_in, const int* in_sizes, int n_in,
                              void* d_out, int out_size, void* d_ws, size_t ws_size,
                              hipStream_t stream) {
    const float* x0 = (const float*)d_in[0];
    const float* x1 = (const float*)d_in[1];
    const int* src = (const int*)d_in[2];
    const int* dst = (const int*)d_in[3];
    const float* ew = (const float*)d_in[4];
    const float* W1 = (const float*)d_in[5];
    const float* Wl = (const float*)d_in[6];
    float* out = (float*)d_out;

    int N = in_sizes[0] / FD;
    int E = in_sizes[2] / NREL;
    int E2 = 2 * E;                 // edges per super-relation
    int NBP = idiv_up(N, BUCKET);   // 196 for N=50000 (must be <= 1024 for bscan)

    char* ws = (char*)d_ws;
    size_t off = 0;
    auto alloc = [&](size_t bytes) -> void* {
        void* p = ws + off;
        off = (off + bytes + 255) & ~(size_t)255;
        return p;
    };
    int* bhist   = (int*)alloc((size_t)NSUP * NBP * 4);
    int* bptr    = (int*)alloc((size_t)NSUP * (NBP + 1) * 4);
    int* gcur    = (int*)alloc((size_t)NSUP * NBP * 4);
    int* rowptr  = (int*)alloc((size_t)NSUP * (N + 1) * 4);
    unsigned int* edges = (unsigned int*)alloc((size_t)NSUP * E2 * 4);
    unsigned short* y    = (unsigned short*)alloc((size_t)NREL * N * HD * 2);
    unsigned short* xb   = (unsigned short*)alloc((size_t)2 * N * FD * 2);
    unsigned short* actb = (unsigned short*)alloc((size_t)2 * N * HD * 2);
    unsigned short* W1f  = (unsigned short*)alloc((size_t)NREL * 4 * 4 * 64 * 8 * 2);
    unsigned short* Wlf  = (unsigned short*)alloc((size_t)16 * 2 * 4 * 64 * 8 * 2);
    int2* staged = (int2*)alloc((size_t)NSUP * E2 * 8);   // dead after bsort
    (void)ws_size;

    // input converts
    int nq = N * FD / 4;
    convx_kernel<<<2048, 256, 0, stream>>>(x0, x1, xb, nq);
    convw_kernel<<<idiv_up(NREL * 4 * 4 * 64, 256), 256, 0, stream>>>(W1, W1f, NREL, 4);
    convw_kernel<<<idiv_up(16 * 2 * 4 * 64, 256), 256, 0, stream>>>(Wl, Wlf, 16, 2);

    // bucket partition + per-bucket counting sort (recomputed every call)
    hipMemsetAsync(bhist, 0, (size_t)NSUP * NBP * 4, stream);
    bhist_kernel<<<dim3(384, NSUP), 256, NBP * 4, stream>>>(dst, bhist, E2, NBP);
    bscan_kernel<<<NSUP, 1024, 0, stream>>>(bhist, bptr, gcur, NBP, E2);
    part_kernel<<<dim3(idiv_up(E2, CHUNK), NSUP), 1024, 2 * NBP * 4, stream>>>(
        src, dst, ew, gcur, staged, E, E2, N, NBP);
    bsort_kernel<<<dim3(NBP, NSUP), 1024, 0, stream>>>(staged, bptr, rowptr, edges, E2, N, NBP);

    dim3 ggrid(idiv_up(N, 128), NREL);
    int NB4 = idiv_up(N, 4);
    int sgx = idiv_up(NB4, 4) * 8;   // flat grid, id%8 -> (type, xcd-slot)

    // layer 1: h1 = relu(spmm(x @ W1)); store act(bf16) + out[:, :, 0:64]
    gemm_mfma_kernel<FD><<<ggrid, 256, 0, stream>>>(xb, W1f, y, N);
    spmm_kernel<<<sgx, 256, 0, stream>>>(y, rowptr, edges, actb, out + 0, N, E2, 1);

    // layers 2..5 with Wl[0..3]
    for (int l = 0; l < 4; ++l) {
        gemm_mfma_kernel<HD><<<ggrid, 256, 0, stream>>>(
            actb, Wlf + (size_t)l * 4 * 2 * 4 * 64 * 8, y, N);
        float* op = (l == 0) ? (out + 64) : (l == 3) ? (out + 128) : nullptr;
        unsigned short* ap = (l == 3) ? nullptr : actb;
        int relu = (l == 3) ? 0 : 1;
        spmm_kernel<<<sgx, 256, 0, stream>>>(y, rowptr, edges, ap, op, N, E2, relu);
    }
}